// Round 8
// baseline (309.444 us; speedup 1.0000x reference)
//
#include <hip/hip_runtime.h>
#include <hip/hip_bf16.h>

#define N_NODES 100000
#define E_EDGES 1600000
#define IN_C 128
#define HID_C 64
#define OUT_C 40

#define NBUCK 196          // ceil(100000 / 512) buckets by dst>>9
#define BCAP 9216          // mean 8192 + 11 sigma
#define B1_EPT 16
#define B1_CHUNK (256 * B1_EPT)   // 4096 edges per block
#define B1_GRID ((E_EDGES + B1_CHUNK - 1) / B1_CHUNK)

typedef unsigned short ushort_t;
typedef unsigned int uint_t;
typedef unsigned char uchar_t;
typedef __attribute__((ext_vector_type(8))) short bf16x8;
typedef __attribute__((ext_vector_type(4))) float f32x4;
typedef __attribute__((ext_vector_type(2))) float f32x2;

__device__ __forceinline__ float bfu2f(ushort_t u) {
    return __uint_as_float(((uint_t)u) << 16);
}
__device__ __forceinline__ ushort_t f2bfu(float f) {   // RNE
    uint_t u = __float_as_uint(f);
    return (ushort_t)((u + 0x7FFFu + ((u >> 16) & 1u)) >> 16);
}
__device__ __forceinline__ uchar_t f2fp8(float f) {    // e4m3 via HW cvt
    int p = __builtin_amdgcn_cvt_pk_fp8_f32(f, f, 0, false);
    return (uchar_t)(p & 0xff);
}
__device__ __forceinline__ float fp8_1(int u) {        // low byte fp8 -> f32
    f32x2 f = __builtin_amdgcn_cvt_pk_f32_fp8(u, false);
    return f.x;
}

// ---------------------------------------------------------------- bucketize edges by dst>>9 (packed: src | dlocal<<17)
__global__ __launch_bounds__(256) void k_bucket(const int* __restrict__ src, const int* __restrict__ dst,
                                                int* __restrict__ bcur, int* __restrict__ bucket) {
    __shared__ int cnt[NBUCK];
    __shared__ int base[NBUCK];
    const int t = threadIdx.x;
    const int e0 = blockIdx.x * B1_CHUNK;

    for (int i = t; i < NBUCK; i += 256) cnt[i] = 0;
    __syncthreads();

    int myp[B1_EPT];
    int myb[B1_EPT];
#pragma unroll
    for (int j = 0; j < B1_EPT; ++j) {
        int e = e0 + t + j * 256;
        if (e < E_EDGES) {
            int d = dst[e];
            myp[j] = src[e] | ((d & 511) << 17);
            myb[j] = d >> 9;
            atomicAdd(&cnt[myb[j]], 1);
        } else {
            myb[j] = -1;
        }
    }
    __syncthreads();
    for (int i = t; i < NBUCK; i += 256) {
        base[i] = atomicAdd(&bcur[i], cnt[i]);
        cnt[i] = 0;
    }
    __syncthreads();
#pragma unroll
    for (int j = 0; j < B1_EPT; ++j) {
        if (myb[j] >= 0) {
            int b = myb[j];
            int loc = atomicAdd(&cnt[b], 1);
            int pos = base[b] + loc;
            if (pos < BCAP) bucket[(size_t)b * BCAP + pos] = myp[j];
        }
    }
}

// ---------------------------------------------------------------- exclusive scan of bucket sizes (1 block)
__global__ __launch_bounds__(256) void k_scanS(const int* __restrict__ bcur, int* __restrict__ bbase,
                                               int* __restrict__ rowptr) {
    __shared__ int tmp[256];
    int t = threadIdx.x;
    int v = (t < NBUCK) ? min(bcur[t], BCAP) : 0;
    tmp[t] = v;
    __syncthreads();
    for (int off = 1; off < 256; off <<= 1) {
        int a = (t >= off) ? tmp[t - off] : 0;
        __syncthreads();
        tmp[t] += a;
        __syncthreads();
    }
    if (t < NBUCK) bbase[t] = tmp[t] - v;
    if (t == 0) rowptr[N_NODES] = tmp[255];
}

// ---------------------------------------------------------------- per-bucket counting sort -> rowptr slice + csr slice
__global__ __launch_bounds__(256) void k_csr(const int* __restrict__ bucket, const int* __restrict__ bcur,
                                             const int* __restrict__ bbase,
                                             int* __restrict__ rowptr, int* __restrict__ csr) {
    __shared__ int hist[512];
    __shared__ int sc[2][512];
    __shared__ int cur[512];
    __shared__ int csrbuf[BCAP];
    const int t = threadIdx.x;
    const int b = blockIdx.x;
    const int n0 = b << 9;
    const int nb = min(512, N_NODES - n0);
    const int sz = min(bcur[b], BCAP);
    const int cbase = bbase[b];
    const int* bdata = bucket + (size_t)b * BCAP;

    for (int i = t; i < 512; i += 256) hist[i] = 0;
    __syncthreads();
    for (int i = t; i < sz; i += 256) {
        int p = bdata[i];
        atomicAdd(&hist[p >> 17], 1);
    }
    __syncthreads();
    for (int i = t; i < 512; i += 256) sc[0][i] = hist[i];
    __syncthreads();
    int pp = 0;
    for (int off = 1; off < 512; off <<= 1) {
        for (int i = t; i < 512; i += 256)
            sc[1 - pp][i] = sc[pp][i] + ((i >= off) ? sc[pp][i - off] : 0);
        __syncthreads();
        pp ^= 1;
    }
    for (int i = t; i < 512; i += 256) {
        int exc = sc[pp][i] - hist[i];
        cur[i] = exc;
        if (i < nb) rowptr[n0 + i] = cbase + exc;
    }
    __syncthreads();
    for (int i = t; i < sz; i += 256) {
        int p = bdata[i];
        int pos = atomicAdd(&cur[p >> 17], 1);
        csrbuf[pos] = p & 0x1FFFF;
    }
    __syncthreads();
    for (int i = t; i < sz; i += 256)
        csr[cbase + i] = csrbuf[i];
}

// ---------------------------------------------------------------- weight prep: bf16, transposed, l|r concatenated
__global__ __launch_bounds__(256) void k_wprep(const float* __restrict__ Wl1, const float* __restrict__ Wr1,
                                               const float* __restrict__ Wl2, const float* __restrict__ Wr2,
                                               ushort_t* __restrict__ Wt1, ushort_t* __restrict__ Wt2) {
    int i = blockIdx.x * 256 + threadIdx.x;
    if (i < 128 * 128) {
        int n = i >> 7, k = i & 127;
        float v = (n < 64) ? Wl1[k * 64 + n] : Wr1[k * 64 + (n - 64)];
        Wt1[n * 128 + k] = f2bfu(v);
    }
    if (i < 80 * 64) {
        int n = i >> 6, k = i & 63;
        float v = (n < 40) ? Wl2[k * 40 + n] : Wr2[k * 40 + (n - 40)];
        Wt2[n * 64 + k] = f2bfu(v);
    }
}

// ---------------------------------------------------------------- GEMM1 (MFMA): [h1l(fp8)|h1r(f32)] = x @ [Wl1|Wr1]
__global__ __launch_bounds__(256) void k_gemm1(const float* __restrict__ x,
                                               const ushort_t* __restrict__ Wt,  // [128][128] bf16
                                               uchar_t* __restrict__ h1l,
                                               float* __restrict__ h1r) {
    __shared__ ushort_t xs[64 * 136];
    __shared__ ushort_t wsm[128 * 136];
    const int t = threadIdx.x;
    const int row_base = blockIdx.x * 64;

    for (int i = t; i < 128 * 16; i += 256) {
        int n = i >> 4, seg = i & 15;
        uint4 v = *(const uint4*)(Wt + n * 128 + seg * 8);
        *(uint4*)(wsm + n * 136 + seg * 8) = v;
    }
    for (int i = t; i < 64 * 32; i += 256) {
        int row = i >> 5, seg = i & 31;
        int gr = row_base + row;
        float4 v = make_float4(0.f, 0.f, 0.f, 0.f);
        if (gr < N_NODES) v = *(const float4*)(x + (size_t)gr * IN_C + seg * 4);
        ushort4 u;
        u.x = f2bfu(v.x); u.y = f2bfu(v.y); u.z = f2bfu(v.z); u.w = f2bfu(v.w);
        *(ushort4*)(xs + row * 136 + seg * 4) = u;
    }
    __syncthreads();

    const int wv = t >> 6, lane = t & 63;
    const int m = lane & 15, quad = lane >> 4;
    const int m0 = wv * 16;

    bf16x8 a[4];
#pragma unroll
    for (int kk = 0; kk < 4; ++kk)
        a[kk] = *(const bf16x8*)(xs + (m0 + m) * 136 + kk * 32 + quad * 8);

    f32x4 acc[8];
#pragma unroll
    for (int nt = 0; nt < 8; ++nt) acc[nt] = (f32x4){0.f, 0.f, 0.f, 0.f};

#pragma unroll
    for (int nt = 0; nt < 8; ++nt) {
#pragma unroll
        for (int kk = 0; kk < 4; ++kk) {
            bf16x8 b = *(const bf16x8*)(wsm + (nt * 16 + m) * 136 + kk * 32 + quad * 8);
            acc[nt] = __builtin_amdgcn_mfma_f32_16x16x32_bf16(a[kk], b, acc[nt], 0, 0, 0);
        }
    }

    const int grow_base = row_base + m0 + quad * 4;
#pragma unroll
    for (int r = 0; r < 4; ++r) {
        int grow = grow_base + r;
        if (grow < N_NODES) {
#pragma unroll
            for (int nt = 0; nt < 4; ++nt)
                h1l[(size_t)grow * HID_C + nt * 16 + m] = f2fp8(acc[nt][r]);
#pragma unroll
            for (int nt = 4; nt < 8; ++nt)
                h1r[(size_t)grow * HID_C + (nt - 4) * 16 + m] = acc[nt][r];
        }
    }
}

// ---------------------------------------------------------------- agg1: lane=channel gather of fp8 h1l (64B rows)
// one wave per dst row; fused relu(mean + root + b1); writes hid bf16
__global__ __launch_bounds__(256) void k_agg1(const int* __restrict__ rowptr, const int* __restrict__ csr,
                                              const uchar_t* __restrict__ h1l, const float* __restrict__ h1r,
                                              const float* __restrict__ b1, ushort_t* __restrict__ hid) {
    int row = (blockIdx.x * 256 + threadIdx.x) >> 6;
    int lane = threadIdx.x & 63;
    if (row >= N_NODES) return;
    int start = rowptr[row];
    int end = rowptr[row + 1];
    const uchar_t* colp = h1l + lane;
    float acc = 0.0f;
    int e = start;
    for (; e + 8 <= end; e += 8) {
        int s0 = csr[e],     s1 = csr[e + 1], s2 = csr[e + 2], s3 = csr[e + 3];
        int s4 = csr[e + 4], s5 = csr[e + 5], s6 = csr[e + 6], s7 = csr[e + 7];
        float v0 = fp8_1(colp[(size_t)s0 << 6]);
        float v1 = fp8_1(colp[(size_t)s1 << 6]);
        float v2 = fp8_1(colp[(size_t)s2 << 6]);
        float v3 = fp8_1(colp[(size_t)s3 << 6]);
        float v4 = fp8_1(colp[(size_t)s4 << 6]);
        float v5 = fp8_1(colp[(size_t)s5 << 6]);
        float v6 = fp8_1(colp[(size_t)s6 << 6]);
        float v7 = fp8_1(colp[(size_t)s7 << 6]);
        acc += ((v0 + v1) + (v2 + v3)) + ((v4 + v5) + (v6 + v7));
    }
    for (; e < end; ++e)
        acc += fp8_1(colp[(size_t)csr[e] << 6]);

    float inv = __builtin_amdgcn_rcpf(fmaxf((float)(end - start), 1.0f));
    float h = fmaxf(acc * inv + h1r[(size_t)row * HID_C + lane] + b1[lane], 0.0f);
    hid[(size_t)row * HID_C + lane] = f2bfu(h);
}

// ---------------------------------------------------------------- GEMM2 (MFMA): [h2l(fp8,stride64)|h2r(f32)] = hid(bf16) @ [Wl2|Wr2]
__global__ __launch_bounds__(256) void k_gemm2(const ushort_t* __restrict__ hid,
                                               const ushort_t* __restrict__ Wt,  // [80][64] bf16
                                               uchar_t* __restrict__ h2l,
                                               float* __restrict__ h2r) {
    __shared__ ushort_t hs[64 * 72];
    __shared__ ushort_t wsm[80 * 72];
    const int t = threadIdx.x;
    const int row_base = blockIdx.x * 64;

    for (int i = t; i < 80 * 8; i += 256) {
        int n = i >> 3, seg = i & 7;
        uint4 v = *(const uint4*)(Wt + n * 64 + seg * 8);
        *(uint4*)(wsm + n * 72 + seg * 8) = v;
    }
    for (int i = t; i < 64 * 8; i += 256) {         // hid: 64 rows x 8 segs of 8 bf16
        int row = i >> 3, seg = i & 7;
        int gr = row_base + row;
        uint4 v = make_uint4(0u, 0u, 0u, 0u);
        if (gr < N_NODES) v = *(const uint4*)(hid + (size_t)gr * HID_C + seg * 8);
        *(uint4*)(hs + row * 72 + seg * 8) = v;
    }
    __syncthreads();

    const int wv = t >> 6, lane = t & 63;
    const int m = lane & 15, quad = lane >> 4;
    const int m0 = wv * 16;

    bf16x8 a[2];
#pragma unroll
    for (int kk = 0; kk < 2; ++kk)
        a[kk] = *(const bf16x8*)(hs + (m0 + m) * 72 + kk * 32 + quad * 8);

    f32x4 acc[5];
#pragma unroll
    for (int nt = 0; nt < 5; ++nt) acc[nt] = (f32x4){0.f, 0.f, 0.f, 0.f};

#pragma unroll
    for (int nt = 0; nt < 5; ++nt) {
#pragma unroll
        for (int kk = 0; kk < 2; ++kk) {
            bf16x8 b = *(const bf16x8*)(wsm + (nt * 16 + m) * 72 + kk * 32 + quad * 8);
            acc[nt] = __builtin_amdgcn_mfma_f32_16x16x32_bf16(a[kk], b, acc[nt], 0, 0, 0);
        }
    }

    const int grow_base = row_base + m0 + quad * 4;
#pragma unroll
    for (int r = 0; r < 4; ++r) {
        int grow = grow_base + r;
        if (grow < N_NODES) {
#pragma unroll
            for (int nt = 0; nt < 5; ++nt) {
                int col = nt * 16 + m;
                float v = acc[nt][r];
                if (col < OUT_C) h2l[(size_t)grow * 64 + col] = f2fp8(v);
                else             h2r[(size_t)grow * OUT_C + (col - OUT_C)] = v;
            }
        }
    }
}

// ---------------------------------------------------------------- agg2: lane=channel gather of fp8 h2l (64B-stride rows)
// one wave per dst row; fused log_softmax(mean + root + b2)
__global__ __launch_bounds__(256) void k_agg2(const int* __restrict__ rowptr, const int* __restrict__ csr,
                                              const uchar_t* __restrict__ h2l, const float* __restrict__ h2r,
                                              const float* __restrict__ b2, float* __restrict__ out) {
    int row = (blockIdx.x * 256 + threadIdx.x) >> 6;
    int lane = threadIdx.x & 63;
    if (row >= N_NODES) return;
    int start = rowptr[row];
    int end = rowptr[row + 1];
    const uchar_t* colp = h2l + lane;
    float acc = 0.0f;
    int e = start;
    for (; e + 8 <= end; e += 8) {
        int s0 = csr[e],     s1 = csr[e + 1], s2 = csr[e + 2], s3 = csr[e + 3];
        int s4 = csr[e + 4], s5 = csr[e + 5], s6 = csr[e + 6], s7 = csr[e + 7];
        float v0 = fp8_1(colp[(size_t)s0 << 6]);
        float v1 = fp8_1(colp[(size_t)s1 << 6]);
        float v2 = fp8_1(colp[(size_t)s2 << 6]);
        float v3 = fp8_1(colp[(size_t)s3 << 6]);
        float v4 = fp8_1(colp[(size_t)s4 << 6]);
        float v5 = fp8_1(colp[(size_t)s5 << 6]);
        float v6 = fp8_1(colp[(size_t)s6 << 6]);
        float v7 = fp8_1(colp[(size_t)s7 << 6]);
        acc += ((v0 + v1) + (v2 + v3)) + ((v4 + v5) + (v6 + v7));
    }
    for (; e < end; ++e)
        acc += fp8_1(colp[(size_t)csr[e] << 6]);

    float inv = __builtin_amdgcn_rcpf(fmaxf((float)(end - start), 1.0f));
    float v = -1e30f;
    if (lane < OUT_C)
        v = acc * inv + h2r[(size_t)row * OUT_C + lane] + b2[lane];
    float m = v;
#pragma unroll
    for (int off = 1; off <= 32; off <<= 1)
        m = fmaxf(m, __shfl_xor(m, off));
    float ex = expf(v - m);
    float s = ex;
#pragma unroll
    for (int off = 1; off <= 32; off <<= 1)
        s += __shfl_xor(s, off);
    float res = v - m - logf(s);
    if (lane < OUT_C)
        out[(size_t)row * OUT_C + lane] = res;
}

// ----------------------------------------------------------------
extern "C" void kernel_launch(void* const* d_in, const int* in_sizes, int n_in,
                              void* d_out, int out_size, void* d_ws, size_t ws_size,
                              hipStream_t stream) {
    const float* x   = (const float*)d_in[0];
    const int*   ei  = (const int*)d_in[1];
    const float* Wl1 = (const float*)d_in[2];
    const float* b1  = (const float*)d_in[3];
    const float* Wr1 = (const float*)d_in[4];
    const float* Wl2 = (const float*)d_in[5];
    const float* b2  = (const float*)d_in[6];
    const float* Wr2 = (const float*)d_in[7];

    // ws layout (4B units): bucket int[196*9216] | bcur | bbase | rowptr[N+1] | csr[E] |
    //   [align16] | Wt1 | Wt2 | h1l fp8[N*64] | h1r f32[N*64] | hid bf16[N*64] |
    //   h2l fp8[N*64] | h2r f32[N*40]
    size_t u = 0;
    int*      bucket = (int*)d_ws;             u += (size_t)NBUCK * BCAP;
    int*      bcur   = (int*)d_ws + u;         u += NBUCK;
    int*      bbase  = (int*)d_ws + u;         u += NBUCK + 4;
    int*      rowptr = (int*)d_ws + u;         u += N_NODES + 1;
    int*      csr    = (int*)d_ws + u;         u += E_EDGES;
    u = (u + 3) & ~(size_t)3;                  // 16B align
    ushort_t* Wt1    = (ushort_t*)((int*)d_ws + u); u += 128 * 128 / 2;
    ushort_t* Wt2    = (ushort_t*)((int*)d_ws + u); u += 80 * 64 / 2;
    uchar_t*  h1l    = (uchar_t*)((int*)d_ws + u);  u += (size_t)N_NODES * HID_C / 4;
    float*    h1r    = (float*)d_ws + u;       u += (size_t)N_NODES * HID_C;
    ushort_t* hid    = (ushort_t*)((int*)d_ws + u); u += (size_t)N_NODES * HID_C / 2;
    uchar_t*  h2l    = (uchar_t*)((int*)d_ws + u);  u += (size_t)N_NODES * 64 / 4;
    float*    h2r    = (float*)d_ws + u;       u += (size_t)N_NODES * OUT_C;
    if (ws_size < u * 4) return;

    hipMemsetAsync(bcur, 0, NBUCK * sizeof(int), stream);

    const int* src = ei;
    const int* dst = ei + E_EDGES;

    k_wprep<<<64, 256, 0, stream>>>(Wl1, Wr1, Wl2, Wr2, Wt1, Wt2);
    k_bucket<<<B1_GRID, 256, 0, stream>>>(src, dst, bcur, bucket);
    k_scanS<<<1, 256, 0, stream>>>(bcur, bbase, rowptr);
    k_csr<<<NBUCK, 256, 0, stream>>>(bucket, bcur, bbase, rowptr, csr);

    k_gemm1<<<(N_NODES + 63) / 64, 256, 0, stream>>>(x, Wt1, h1l, h1r);
    k_agg1<<<N_NODES / 4, 256, 0, stream>>>(rowptr, csr, h1l, h1r, b1, hid);
    k_gemm2<<<(N_NODES + 63) / 64, 256, 0, stream>>>(hid, Wt2, h2l, h2r);
    k_agg2<<<N_NODES / 4, 256, 0, stream>>>(rowptr, csr, h2l, h2r, b2, (float*)d_out);
}

// Round 9
// 277.081 us; speedup vs baseline: 1.1168x; 1.1168x over previous
//
#include <hip/hip_runtime.h>
#include <hip/hip_bf16.h>

#define N_NODES 100000
#define E_EDGES 1600000
#define IN_C 128
#define HID_C 64
#define OUT_C 40

#define NBUCK 196          // ceil(100000 / 512) buckets by dst>>9
#define BCAP 9216          // mean 8192 + 11 sigma
#define B1_EPT 16
#define B1_CHUNK (256 * B1_EPT)   // 4096 edges per block
#define B1_GRID ((E_EDGES + B1_CHUNK - 1) / B1_CHUNK)

typedef unsigned short ushort_t;
typedef unsigned int uint_t;
typedef unsigned char uchar_t;
typedef __attribute__((ext_vector_type(8))) short bf16x8;
typedef __attribute__((ext_vector_type(4))) float f32x4;
typedef __attribute__((ext_vector_type(2))) float f32x2;

__device__ __forceinline__ float bfu2f(ushort_t u) {
    return __uint_as_float(((uint_t)u) << 16);
}
__device__ __forceinline__ ushort_t f2bfu(float f) {   // RNE
    uint_t u = __float_as_uint(f);
    return (ushort_t)((u + 0x7FFFu + ((u >> 16) & 1u)) >> 16);
}
__device__ __forceinline__ uchar_t f2fp8(float f) {    // e4m3 via HW cvt
    int p = __builtin_amdgcn_cvt_pk_fp8_f32(f, f, 0, false);
    return (uchar_t)(p & 0xff);
}

// ---------------------------------------------------------------- bucketize edges by dst>>9 (packed: src | dlocal<<17)
__global__ __launch_bounds__(256) void k_bucket(const int* __restrict__ src, const int* __restrict__ dst,
                                                int* __restrict__ bcur, int* __restrict__ bucket) {
    __shared__ int cnt[NBUCK];
    __shared__ int base[NBUCK];
    const int t = threadIdx.x;
    const int e0 = blockIdx.x * B1_CHUNK;

    for (int i = t; i < NBUCK; i += 256) cnt[i] = 0;
    __syncthreads();

    int myp[B1_EPT];
    int myb[B1_EPT];
#pragma unroll
    for (int j = 0; j < B1_EPT; ++j) {
        int e = e0 + t + j * 256;
        if (e < E_EDGES) {
            int d = dst[e];
            myp[j] = src[e] | ((d & 511) << 17);
            myb[j] = d >> 9;
            atomicAdd(&cnt[myb[j]], 1);
        } else {
            myb[j] = -1;
        }
    }
    __syncthreads();
    for (int i = t; i < NBUCK; i += 256) {
        base[i] = atomicAdd(&bcur[i], cnt[i]);
        cnt[i] = 0;
    }
    __syncthreads();
#pragma unroll
    for (int j = 0; j < B1_EPT; ++j) {
        if (myb[j] >= 0) {
            int b = myb[j];
            int loc = atomicAdd(&cnt[b], 1);
            int pos = base[b] + loc;
            if (pos < BCAP) bucket[(size_t)b * BCAP + pos] = myp[j];
        }
    }
}

// ---------------------------------------------------------------- exclusive scan of bucket sizes (1 block)
__global__ __launch_bounds__(256) void k_scanS(const int* __restrict__ bcur, int* __restrict__ bbase,
                                               int* __restrict__ rowptr) {
    __shared__ int tmp[256];
    int t = threadIdx.x;
    int v = (t < NBUCK) ? min(bcur[t], BCAP) : 0;
    tmp[t] = v;
    __syncthreads();
    for (int off = 1; off < 256; off <<= 1) {
        int a = (t >= off) ? tmp[t - off] : 0;
        __syncthreads();
        tmp[t] += a;
        __syncthreads();
    }
    if (t < NBUCK) bbase[t] = tmp[t] - v;
    if (t == 0) rowptr[N_NODES] = tmp[255];
}

// ---------------------------------------------------------------- per-bucket counting sort -> rowptr slice + csr slice
__global__ __launch_bounds__(256) void k_csr(const int* __restrict__ bucket, const int* __restrict__ bcur,
                                             const int* __restrict__ bbase,
                                             int* __restrict__ rowptr, int* __restrict__ csr) {
    __shared__ int hist[512];
    __shared__ int sc[2][512];
    __shared__ int cur[512];
    __shared__ int csrbuf[BCAP];
    const int t = threadIdx.x;
    const int b = blockIdx.x;
    const int n0 = b << 9;
    const int nb = min(512, N_NODES - n0);
    const int sz = min(bcur[b], BCAP);
    const int cbase = bbase[b];
    const int* bdata = bucket + (size_t)b * BCAP;

    for (int i = t; i < 512; i += 256) hist[i] = 0;
    __syncthreads();
    for (int i = t; i < sz; i += 256) {
        int p = bdata[i];
        atomicAdd(&hist[p >> 17], 1);
    }
    __syncthreads();
    for (int i = t; i < 512; i += 256) sc[0][i] = hist[i];
    __syncthreads();
    int pp = 0;
    for (int off = 1; off < 512; off <<= 1) {
        for (int i = t; i < 512; i += 256)
            sc[1 - pp][i] = sc[pp][i] + ((i >= off) ? sc[pp][i - off] : 0);
        __syncthreads();
        pp ^= 1;
    }
    for (int i = t; i < 512; i += 256) {
        int exc = sc[pp][i] - hist[i];
        cur[i] = exc;
        if (i < nb) rowptr[n0 + i] = cbase + exc;
    }
    __syncthreads();
    for (int i = t; i < sz; i += 256) {
        int p = bdata[i];
        int pos = atomicAdd(&cur[p >> 17], 1);
        csrbuf[pos] = p & 0x1FFFF;
    }
    __syncthreads();
    for (int i = t; i < sz; i += 256)
        csr[cbase + i] = csrbuf[i];
}

// ---------------------------------------------------------------- weight prep: bf16, transposed, l|r concatenated
__global__ __launch_bounds__(256) void k_wprep(const float* __restrict__ Wl1, const float* __restrict__ Wr1,
                                               const float* __restrict__ Wl2, const float* __restrict__ Wr2,
                                               ushort_t* __restrict__ Wt1, ushort_t* __restrict__ Wt2) {
    int i = blockIdx.x * 256 + threadIdx.x;
    if (i < 128 * 128) {
        int n = i >> 7, k = i & 127;
        float v = (n < 64) ? Wl1[k * 64 + n] : Wr1[k * 64 + (n - 64)];
        Wt1[n * 128 + k] = f2bfu(v);
    }
    if (i < 80 * 64) {
        int n = i >> 6, k = i & 63;
        float v = (n < 40) ? Wl2[k * 40 + n] : Wr2[k * 40 + (n - 40)];
        Wt2[n * 64 + k] = f2bfu(v);
    }
}

// ---------------------------------------------------------------- GEMM1 (MFMA): [h1l(fp8)|h1r(f32)] = x @ [Wl1|Wr1]
__global__ __launch_bounds__(256) void k_gemm1(const float* __restrict__ x,
                                               const ushort_t* __restrict__ Wt,  // [128][128] bf16
                                               uchar_t* __restrict__ h1l,
                                               float* __restrict__ h1r) {
    __shared__ ushort_t xs[64 * 136];
    __shared__ ushort_t wsm[128 * 136];
    const int t = threadIdx.x;
    const int row_base = blockIdx.x * 64;

    for (int i = t; i < 128 * 16; i += 256) {
        int n = i >> 4, seg = i & 15;
        uint4 v = *(const uint4*)(Wt + n * 128 + seg * 8);
        *(uint4*)(wsm + n * 136 + seg * 8) = v;
    }
    for (int i = t; i < 64 * 32; i += 256) {
        int row = i >> 5, seg = i & 31;
        int gr = row_base + row;
        float4 v = make_float4(0.f, 0.f, 0.f, 0.f);
        if (gr < N_NODES) v = *(const float4*)(x + (size_t)gr * IN_C + seg * 4);
        ushort4 u;
        u.x = f2bfu(v.x); u.y = f2bfu(v.y); u.z = f2bfu(v.z); u.w = f2bfu(v.w);
        *(ushort4*)(xs + row * 136 + seg * 4) = u;
    }
    __syncthreads();

    const int wv = t >> 6, lane = t & 63;
    const int m = lane & 15, quad = lane >> 4;
    const int m0 = wv * 16;

    bf16x8 a[4];
#pragma unroll
    for (int kk = 0; kk < 4; ++kk)
        a[kk] = *(const bf16x8*)(xs + (m0 + m) * 136 + kk * 32 + quad * 8);

    f32x4 acc[8];
#pragma unroll
    for (int nt = 0; nt < 8; ++nt) acc[nt] = (f32x4){0.f, 0.f, 0.f, 0.f};

#pragma unroll
    for (int nt = 0; nt < 8; ++nt) {
#pragma unroll
        for (int kk = 0; kk < 4; ++kk) {
            bf16x8 b = *(const bf16x8*)(wsm + (nt * 16 + m) * 136 + kk * 32 + quad * 8);
            acc[nt] = __builtin_amdgcn_mfma_f32_16x16x32_bf16(a[kk], b, acc[nt], 0, 0, 0);
        }
    }

    const int grow_base = row_base + m0 + quad * 4;
#pragma unroll
    for (int r = 0; r < 4; ++r) {
        int grow = grow_base + r;
        if (grow < N_NODES) {
#pragma unroll
            for (int nt = 0; nt < 4; ++nt)
                h1l[(size_t)grow * HID_C + nt * 16 + m] = f2fp8(acc[nt][r]);
#pragma unroll
            for (int nt = 4; nt < 8; ++nt)
                h1r[(size_t)grow * HID_C + (nt - 4) * 16 + m] = acc[nt][r];
        }
    }
}

// ---------------------------------------------------------------- agg1: 8-slot uint2 gather of fp8 h1l (64B rows)
// slot=lane>>3 (8 edges/iter, 8 lines/inst), part=lane&7 (8 ch); static-xor reduce; writes hid bf16
__global__ __launch_bounds__(256) void k_agg1(const int* __restrict__ rowptr, const int* __restrict__ csr,
                                              const uchar_t* __restrict__ h1l, const float* __restrict__ h1r,
                                              const float* __restrict__ b1, ushort_t* __restrict__ hid) {
    int row = (blockIdx.x * 256 + threadIdx.x) >> 6;
    int lane = threadIdx.x & 63;
    if (row >= N_NODES) return;
    int start = rowptr[row];
    int end = rowptr[row + 1];
    const int slot = lane >> 3;
    const int part = lane & 7;
    float acc[8] = {0.f, 0.f, 0.f, 0.f, 0.f, 0.f, 0.f, 0.f};

    for (int base = start; base < end; base += 8) {
        int e = base + slot;
        int ee = min(e, end - 1);
        int s = csr[ee];
        uint2 u = *(const uint2*)(h1l + ((size_t)s << 6) + part * 8);
        if (e >= end) { u.x = 0u; u.y = 0u; }
        f32x2 f;
        f = __builtin_amdgcn_cvt_pk_f32_fp8(u.x, false); acc[0] += f.x; acc[1] += f.y;
        f = __builtin_amdgcn_cvt_pk_f32_fp8(u.x, true);  acc[2] += f.x; acc[3] += f.y;
        f = __builtin_amdgcn_cvt_pk_f32_fp8(u.y, false); acc[4] += f.x; acc[5] += f.y;
        f = __builtin_amdgcn_cvt_pk_f32_fp8(u.y, true);  acc[6] += f.x; acc[7] += f.y;
    }
#pragma unroll
    for (int off = 8; off <= 32; off <<= 1)
#pragma unroll
        for (int j = 0; j < 8; ++j)
            acc[j] += __shfl_xor(acc[j], off);

    if (slot == 0) {   // lanes 0..7 hold channels part*8 .. part*8+7
        float inv = __builtin_amdgcn_rcpf(fmaxf((float)(end - start), 1.0f));
        size_t bi = (size_t)row * HID_C + part * 8;
        float4 r0 = *(const float4*)(h1r + bi);
        float4 r1 = *(const float4*)(h1r + bi + 4);
        float4 bb0 = *(const float4*)(b1 + part * 8);
        float4 bb1 = *(const float4*)(b1 + part * 8 + 4);
        ushort_t o[8];
        o[0] = f2bfu(fmaxf(acc[0] * inv + r0.x + bb0.x, 0.f));
        o[1] = f2bfu(fmaxf(acc[1] * inv + r0.y + bb0.y, 0.f));
        o[2] = f2bfu(fmaxf(acc[2] * inv + r0.z + bb0.z, 0.f));
        o[3] = f2bfu(fmaxf(acc[3] * inv + r0.w + bb0.w, 0.f));
        o[4] = f2bfu(fmaxf(acc[4] * inv + r1.x + bb1.x, 0.f));
        o[5] = f2bfu(fmaxf(acc[5] * inv + r1.y + bb1.y, 0.f));
        o[6] = f2bfu(fmaxf(acc[6] * inv + r1.z + bb1.z, 0.f));
        o[7] = f2bfu(fmaxf(acc[7] * inv + r1.w + bb1.w, 0.f));
        *(uint4*)(hid + bi) = *(const uint4*)o;
    }
}

// ---------------------------------------------------------------- GEMM2 (MFMA): [h2l(fp8,stride64)|h2r(f32)] = hid(bf16) @ [Wl2|Wr2]
__global__ __launch_bounds__(256) void k_gemm2(const ushort_t* __restrict__ hid,
                                               const ushort_t* __restrict__ Wt,  // [80][64] bf16
                                               uchar_t* __restrict__ h2l,
                                               float* __restrict__ h2r) {
    __shared__ ushort_t hs[64 * 72];
    __shared__ ushort_t wsm[80 * 72];
    const int t = threadIdx.x;
    const int row_base = blockIdx.x * 64;

    for (int i = t; i < 80 * 8; i += 256) {
        int n = i >> 3, seg = i & 7;
        uint4 v = *(const uint4*)(Wt + n * 64 + seg * 8);
        *(uint4*)(wsm + n * 72 + seg * 8) = v;
    }
    for (int i = t; i < 64 * 8; i += 256) {
        int row = i >> 3, seg = i & 7;
        int gr = row_base + row;
        uint4 v = make_uint4(0u, 0u, 0u, 0u);
        if (gr < N_NODES) v = *(const uint4*)(hid + (size_t)gr * HID_C + seg * 8);
        *(uint4*)(hs + row * 72 + seg * 8) = v;
    }
    __syncthreads();

    const int wv = t >> 6, lane = t & 63;
    const int m = lane & 15, quad = lane >> 4;
    const int m0 = wv * 16;

    bf16x8 a[2];
#pragma unroll
    for (int kk = 0; kk < 2; ++kk)
        a[kk] = *(const bf16x8*)(hs + (m0 + m) * 72 + kk * 32 + quad * 8);

    f32x4 acc[5];
#pragma unroll
    for (int nt = 0; nt < 5; ++nt) acc[nt] = (f32x4){0.f, 0.f, 0.f, 0.f};

#pragma unroll
    for (int nt = 0; nt < 5; ++nt) {
#pragma unroll
        for (int kk = 0; kk < 2; ++kk) {
            bf16x8 b = *(const bf16x8*)(wsm + (nt * 16 + m) * 72 + kk * 32 + quad * 8);
            acc[nt] = __builtin_amdgcn_mfma_f32_16x16x32_bf16(a[kk], b, acc[nt], 0, 0, 0);
        }
    }

    const int grow_base = row_base + m0 + quad * 4;
#pragma unroll
    for (int r = 0; r < 4; ++r) {
        int grow = grow_base + r;
        if (grow < N_NODES) {
#pragma unroll
            for (int nt = 0; nt < 5; ++nt) {
                int col = nt * 16 + m;
                float v = acc[nt][r];
                if (col < OUT_C) h2l[(size_t)grow * 64 + col] = f2fp8(v);
                else             h2r[(size_t)grow * OUT_C + (col - OUT_C)] = v;
            }
        }
    }
}

// ---------------------------------------------------------------- agg2: 8-slot uint2 gather of fp8 h2l (40B data in 64B stride)
// static-xor reduce; fused log_softmax. One wave per dst row.
__global__ __launch_bounds__(256) void k_agg2(const int* __restrict__ rowptr, const int* __restrict__ csr,
                                              const uchar_t* __restrict__ h2l, const float* __restrict__ h2r,
                                              const float* __restrict__ b2, float* __restrict__ out) {
    int row = (blockIdx.x * 256 + threadIdx.x) >> 6;
    int lane = threadIdx.x & 63;
    if (row >= N_NODES) return;
    int start = rowptr[row];
    int end = rowptr[row + 1];
    const int slot = lane >> 3;
    const int part = lane & 7;
    const bool pvalid = part < 5;        // bytes 40..63 are uninitialized
    float acc[8] = {0.f, 0.f, 0.f, 0.f, 0.f, 0.f, 0.f, 0.f};

    for (int base = start; base < end; base += 8) {
        int e = base + slot;
        int ee = min(e, end - 1);
        int s = csr[ee];
        uint2 u = *(const uint2*)(h2l + ((size_t)s << 6) + part * 8);
        if (e >= end || !pvalid) { u.x = 0u; u.y = 0u; }
        f32x2 f;
        f = __builtin_amdgcn_cvt_pk_f32_fp8(u.x, false); acc[0] += f.x; acc[1] += f.y;
        f = __builtin_amdgcn_cvt_pk_f32_fp8(u.x, true);  acc[2] += f.x; acc[3] += f.y;
        f = __builtin_amdgcn_cvt_pk_f32_fp8(u.y, false); acc[4] += f.x; acc[5] += f.y;
        f = __builtin_amdgcn_cvt_pk_f32_fp8(u.y, true);  acc[6] += f.x; acc[7] += f.y;
    }
#pragma unroll
    for (int off = 8; off <= 32; off <<= 1)
#pragma unroll
        for (int j = 0; j < 8; ++j)
            acc[j] += __shfl_xor(acc[j], off);

    // slot-0 lanes 0..4 hold channels part*8 .. part*8+7
    const bool fin = (slot == 0) && pvalid;
    float inv = __builtin_amdgcn_rcpf(fmaxf((float)(end - start), 1.0f));
    float v[8];
    if (fin) {
        size_t bi = (size_t)row * OUT_C + part * 8;
        float4 r0 = *(const float4*)(h2r + bi);
        float4 r1 = *(const float4*)(h2r + bi + 4);
        float4 bb0 = *(const float4*)(b2 + part * 8);
        float4 bb1 = *(const float4*)(b2 + part * 8 + 4);
        v[0] = acc[0] * inv + r0.x + bb0.x;
        v[1] = acc[1] * inv + r0.y + bb0.y;
        v[2] = acc[2] * inv + r0.z + bb0.z;
        v[3] = acc[3] * inv + r0.w + bb0.w;
        v[4] = acc[4] * inv + r1.x + bb1.x;
        v[5] = acc[5] * inv + r1.y + bb1.y;
        v[6] = acc[6] * inv + r1.z + bb1.z;
        v[7] = acc[7] * inv + r1.w + bb1.w;
    } else {
#pragma unroll
        for (int j = 0; j < 8; ++j) v[j] = -1e30f;
    }
    // softmax stats within the 8-lane group (lanes 0..7; others compute garbage, don't write)
    float pm = v[0];
#pragma unroll
    for (int j = 1; j < 8; ++j) pm = fmaxf(pm, v[j]);
#pragma unroll
    for (int off = 1; off <= 4; off <<= 1) pm = fmaxf(pm, __shfl_xor(pm, off));
    float es = 0.f;
#pragma unroll
    for (int j = 0; j < 8; ++j) es += expf(v[j] - pm);
#pragma unroll
    for (int off = 1; off <= 4; off <<= 1) es += __shfl_xor(es, off);
    float ls = logf(es);
    if (fin) {
        size_t bo = (size_t)row * OUT_C + part * 8;
        *(float4*)(out + bo) = make_float4(v[0] - pm - ls, v[1] - pm - ls, v[2] - pm - ls, v[3] - pm - ls);
        *(float4*)(out + bo + 4) = make_float4(v[4] - pm - ls, v[5] - pm - ls, v[6] - pm - ls, v[7] - pm - ls);
    }
}

// ----------------------------------------------------------------
extern "C" void kernel_launch(void* const* d_in, const int* in_sizes, int n_in,
                              void* d_out, int out_size, void* d_ws, size_t ws_size,
                              hipStream_t stream) {
    const float* x   = (const float*)d_in[0];
    const int*   ei  = (const int*)d_in[1];
    const float* Wl1 = (const float*)d_in[2];
    const float* b1  = (const float*)d_in[3];
    const float* Wr1 = (const float*)d_in[4];
    const float* Wl2 = (const float*)d_in[5];
    const float* b2  = (const float*)d_in[6];
    const float* Wr2 = (const float*)d_in[7];

    // ws layout (4B units): bucket int[196*9216] | bcur | bbase | rowptr[N+1] | csr[E] |
    //   [align16] | Wt1 | Wt2 | h1l fp8[N*64] | h1r f32[N*64] | hid bf16[N*64] |
    //   h2l fp8[N*64] | h2r f32[N*40]
    size_t u = 0;
    int*      bucket = (int*)d_ws;             u += (size_t)NBUCK * BCAP;
    int*      bcur   = (int*)d_ws + u;         u += NBUCK;
    int*      bbase  = (int*)d_ws + u;         u += NBUCK + 4;
    int*      rowptr = (int*)d_ws + u;         u += N_NODES + 1;
    int*      csr    = (int*)d_ws + u;         u += E_EDGES;
    u = (u + 3) & ~(size_t)3;                  // 16B align
    ushort_t* Wt1    = (ushort_t*)((int*)d_ws + u); u += 128 * 128 / 2;
    ushort_t* Wt2    = (ushort_t*)((int*)d_ws + u); u += 80 * 64 / 2;
    uchar_t*  h1l    = (uchar_t*)((int*)d_ws + u);  u += (size_t)N_NODES * HID_C / 4;
    float*    h1r    = (float*)d_ws + u;       u += (size_t)N_NODES * HID_C;
    ushort_t* hid    = (ushort_t*)((int*)d_ws + u); u += (size_t)N_NODES * HID_C / 2;
    uchar_t*  h2l    = (uchar_t*)((int*)d_ws + u);  u += (size_t)N_NODES * 64 / 4;
    float*    h2r    = (float*)d_ws + u;       u += (size_t)N_NODES * OUT_C;
    if (ws_size < u * 4) return;

    hipMemsetAsync(bcur, 0, NBUCK * sizeof(int), stream);

    const int* src = ei;
    const int* dst = ei + E_EDGES;

    k_wprep<<<64, 256, 0, stream>>>(Wl1, Wr1, Wl2, Wr2, Wt1, Wt2);
    k_bucket<<<B1_GRID, 256, 0, stream>>>(src, dst, bcur, bucket);
    k_scanS<<<1, 256, 0, stream>>>(bcur, bbase, rowptr);
    k_csr<<<NBUCK, 256, 0, stream>>>(bucket, bcur, bbase, rowptr, csr);

    k_gemm1<<<(N_NODES + 63) / 64, 256, 0, stream>>>(x, Wt1, h1l, h1r);
    k_agg1<<<N_NODES / 4, 256, 0, stream>>>(rowptr, csr, h1l, h1r, b1, hid);
    k_gemm2<<<(N_NODES + 63) / 64, 256, 0, stream>>>(hid, Wt2, h2l, h2r);
    k_agg2<<<N_NODES / 4, 256, 0, stream>>>(rowptr, csr, h2l, h2r, b2, (float*)d_out);
}

// Round 10
// 264.293 us; speedup vs baseline: 1.1708x; 1.0484x over previous
//
#include <hip/hip_runtime.h>
#include <hip/hip_bf16.h>

#define N_NODES 100000
#define E_EDGES 1600000
#define IN_C 128
#define HID_C 64
#define OUT_C 40

#define NBUCK 196          // ceil(100000 / 512) buckets by dst>>9
#define BCAP 9216          // mean 8192 + 11 sigma
#define B1_EPT 16
#define B1_CHUNK (256 * B1_EPT)   // 4096 edges per block
#define B1_GRID ((E_EDGES + B1_CHUNK - 1) / B1_CHUNK)
#define GEMM1_GRID ((N_NODES + 63) / 64)

typedef unsigned short ushort_t;
typedef unsigned int uint_t;
typedef unsigned char uchar_t;
typedef __attribute__((ext_vector_type(8))) short bf16x8;
typedef __attribute__((ext_vector_type(4))) float f32x4;
typedef __attribute__((ext_vector_type(2))) float f32x2;

__device__ __forceinline__ float bfu2f(ushort_t u) {
    return __uint_as_float(((uint_t)u) << 16);
}
__device__ __forceinline__ ushort_t f2bfu(float f) {   // RNE
    uint_t u = __float_as_uint(f);
    return (ushort_t)((u + 0x7FFFu + ((u >> 16) & 1u)) >> 16);
}
__device__ __forceinline__ uchar_t f2fp8(float f) {    // e4m3 via HW cvt
    int p = __builtin_amdgcn_cvt_pk_fp8_f32(f, f, 0, false);
    return (uchar_t)(p & 0xff);
}

// ================================================================ K1: bucket (blocks 0..B1_GRID-1) || wprep (rest)
__global__ __launch_bounds__(256) void k_prep(const int* __restrict__ src, const int* __restrict__ dst,
                                              int* __restrict__ bcur, int* __restrict__ bucket,
                                              const float* __restrict__ Wl1, const float* __restrict__ Wr1,
                                              const float* __restrict__ Wl2, const float* __restrict__ Wr2,
                                              ushort_t* __restrict__ Wt1, ushort_t* __restrict__ Wt2) {
    __shared__ int cnt[NBUCK];
    __shared__ int base[NBUCK];
    const int t = threadIdx.x;

    if (blockIdx.x < B1_GRID) {
        // ---- bucketize edges by dst>>9 (packed: src | dlocal<<17)
        const int e0 = blockIdx.x * B1_CHUNK;
        for (int i = t; i < NBUCK; i += 256) cnt[i] = 0;
        __syncthreads();

        int myp[B1_EPT];
        int myb[B1_EPT];
#pragma unroll
        for (int j = 0; j < B1_EPT; ++j) {
            int e = e0 + t + j * 256;
            if (e < E_EDGES) {
                int d = dst[e];
                myp[j] = src[e] | ((d & 511) << 17);
                myb[j] = d >> 9;
                atomicAdd(&cnt[myb[j]], 1);
            } else {
                myb[j] = -1;
            }
        }
        __syncthreads();
        for (int i = t; i < NBUCK; i += 256) {
            base[i] = atomicAdd(&bcur[i], cnt[i]);
            cnt[i] = 0;
        }
        __syncthreads();
#pragma unroll
        for (int j = 0; j < B1_EPT; ++j) {
            if (myb[j] >= 0) {
                int b = myb[j];
                int loc = atomicAdd(&cnt[b], 1);
                int pos = base[b] + loc;
                if (pos < BCAP) bucket[(size_t)b * BCAP + pos] = myp[j];
            }
        }
    } else {
        // ---- weight prep: bf16, transposed, l|r concatenated
        int i = (blockIdx.x - B1_GRID) * 256 + t;
        if (i < 128 * 128) {
            int n = i >> 7, k = i & 127;
            float v = (n < 64) ? Wl1[k * 64 + n] : Wr1[k * 64 + (n - 64)];
            Wt1[n * 128 + k] = f2bfu(v);
        }
        if (i < 80 * 64) {
            int n = i >> 6, k = i & 63;
            float v = (n < 40) ? Wl2[k * 40 + n] : Wr2[k * 40 + (n - 40)];
            Wt2[n * 64 + k] = f2bfu(v);
        }
    }
}

// ================================================================ K2: csr (blocks 0..NBUCK-1) || gemm1 (rest)
struct SmemCsr {
    int red[256];
    int hist[512];
    int sc[2][512];
    int cur[512];
    int csrbuf[BCAP];
};
struct SmemGemm1 {
    ushort_t xs[64 * 136];
    ushort_t wsm[128 * 136];
};
union SmemK2 {
    SmemCsr c;
    SmemGemm1 g;
};

__global__ __launch_bounds__(256) void k_csr_gemm1(const int* __restrict__ bucket, const int* __restrict__ bcur,
                                                   int* __restrict__ rowptr, int* __restrict__ csr,
                                                   const float* __restrict__ x, const ushort_t* __restrict__ Wt,
                                                   uchar_t* __restrict__ h1l, ushort_t* __restrict__ h1r) {
    __shared__ SmemK2 sm;
    const int t = threadIdx.x;

    if (blockIdx.x < NBUCK) {
        // ---- per-bucket counting sort -> rowptr slice + csr slice (inline exclusive base)
        const int b = blockIdx.x;
        const int n0 = b << 9;
        const int nb = min(512, N_NODES - n0);
        const int sz = min(bcur[b], BCAP);
        const int* bdata = bucket + (size_t)b * BCAP;

        int v = (t < b) ? min(bcur[t], BCAP) : 0;   // NBUCK=196 <= 256
        sm.c.red[t] = v;
        __syncthreads();
        for (int off = 128; off > 0; off >>= 1) {
            if (t < off) sm.c.red[t] += sm.c.red[t + off];
            __syncthreads();
        }
        const int cbase = sm.c.red[0];

        for (int i = t; i < 512; i += 256) sm.c.hist[i] = 0;
        __syncthreads();
        for (int i = t; i < sz; i += 256) {
            int p = bdata[i];
            atomicAdd(&sm.c.hist[p >> 17], 1);
        }
        __syncthreads();
        for (int i = t; i < 512; i += 256) sm.c.sc[0][i] = sm.c.hist[i];
        __syncthreads();
        int pp = 0;
        for (int off = 1; off < 512; off <<= 1) {
            for (int i = t; i < 512; i += 256)
                sm.c.sc[1 - pp][i] = sm.c.sc[pp][i] + ((i >= off) ? sm.c.sc[pp][i - off] : 0);
            __syncthreads();
            pp ^= 1;
        }
        for (int i = t; i < 512; i += 256) {
            int exc = sm.c.sc[pp][i] - sm.c.hist[i];
            sm.c.cur[i] = exc;
            if (i < nb) rowptr[n0 + i] = cbase + exc;
        }
        __syncthreads();
        for (int i = t; i < sz; i += 256) {
            int p = bdata[i];
            int pos = atomicAdd(&sm.c.cur[p >> 17], 1);
            sm.c.csrbuf[pos] = p & 0x1FFFF;
        }
        __syncthreads();
        for (int i = t; i < sz; i += 256)
            csr[cbase + i] = sm.c.csrbuf[i];
        if (b == NBUCK - 1 && t == 0) rowptr[N_NODES] = cbase + sz;
    } else {
        // ---- GEMM1 (MFMA): [h1l(fp8) | h1r(bf16)] = x @ [Wl1|Wr1]
        const int row_base = (blockIdx.x - NBUCK) * 64;

        for (int i = t; i < 128 * 16; i += 256) {
            int n = i >> 4, seg = i & 15;
            uint4 v = *(const uint4*)(Wt + n * 128 + seg * 8);
            *(uint4*)(sm.g.wsm + n * 136 + seg * 8) = v;
        }
        for (int i = t; i < 64 * 32; i += 256) {
            int row = i >> 5, seg = i & 31;
            int gr = row_base + row;
            float4 v = make_float4(0.f, 0.f, 0.f, 0.f);
            if (gr < N_NODES) v = *(const float4*)(x + (size_t)gr * IN_C + seg * 4);
            ushort4 u;
            u.x = f2bfu(v.x); u.y = f2bfu(v.y); u.z = f2bfu(v.z); u.w = f2bfu(v.w);
            *(ushort4*)(sm.g.xs + row * 136 + seg * 4) = u;
        }
        __syncthreads();

        const int wv = t >> 6, lane = t & 63;
        const int m = lane & 15, quad = lane >> 4;
        const int m0 = wv * 16;

        bf16x8 a[4];
#pragma unroll
        for (int kk = 0; kk < 4; ++kk)
            a[kk] = *(const bf16x8*)(sm.g.xs + (m0 + m) * 136 + kk * 32 + quad * 8);

        f32x4 acc[8];
#pragma unroll
        for (int nt = 0; nt < 8; ++nt) acc[nt] = (f32x4){0.f, 0.f, 0.f, 0.f};

#pragma unroll
        for (int nt = 0; nt < 8; ++nt) {
#pragma unroll
            for (int kk = 0; kk < 4; ++kk) {
                bf16x8 b = *(const bf16x8*)(sm.g.wsm + (nt * 16 + m) * 136 + kk * 32 + quad * 8);
                acc[nt] = __builtin_amdgcn_mfma_f32_16x16x32_bf16(a[kk], b, acc[nt], 0, 0, 0);
            }
        }

        const int grow_base = row_base + m0 + quad * 4;
#pragma unroll
        for (int r = 0; r < 4; ++r) {
            int grow = grow_base + r;
            if (grow < N_NODES) {
#pragma unroll
                for (int nt = 0; nt < 4; ++nt)
                    h1l[(size_t)grow * HID_C + nt * 16 + m] = f2fp8(acc[nt][r]);
#pragma unroll
                for (int nt = 4; nt < 8; ++nt)
                    h1r[(size_t)grow * HID_C + (nt - 4) * 16 + m] = f2bfu(acc[nt][r]);
            }
        }
    }
}

// ================================================================ agg1: 8-slot uint2 gather of fp8 h1l (64B rows)
// clean loop + masked remainder; static-xor reduce; root h1r bf16; writes hid bf16
__global__ __launch_bounds__(256) void k_agg1(const int* __restrict__ rowptr, const int* __restrict__ csr,
                                              const uchar_t* __restrict__ h1l, const ushort_t* __restrict__ h1r,
                                              const float* __restrict__ b1, ushort_t* __restrict__ hid) {
    int row = (blockIdx.x * 256 + threadIdx.x) >> 6;
    int lane = threadIdx.x & 63;
    if (row >= N_NODES) return;
    int start = rowptr[row];
    int end = rowptr[row + 1];
    const int slot = lane >> 3;
    const int part = lane & 7;
    float acc[8] = {0.f, 0.f, 0.f, 0.f, 0.f, 0.f, 0.f, 0.f};

    int base = start;
    for (; base + 8 <= end; base += 8) {
        int s = csr[base + slot];
        uint2 u = *(const uint2*)(h1l + ((size_t)s << 6) + part * 8);
        f32x2 f;
        f = __builtin_amdgcn_cvt_pk_f32_fp8(u.x, false); acc[0] += f.x; acc[1] += f.y;
        f = __builtin_amdgcn_cvt_pk_f32_fp8(u.x, true);  acc[2] += f.x; acc[3] += f.y;
        f = __builtin_amdgcn_cvt_pk_f32_fp8(u.y, false); acc[4] += f.x; acc[5] += f.y;
        f = __builtin_amdgcn_cvt_pk_f32_fp8(u.y, true);  acc[6] += f.x; acc[7] += f.y;
    }
    if (base < end) {
        int e = base + slot;
        int s = csr[min(e, end - 1)];
        uint2 u = *(const uint2*)(h1l + ((size_t)s << 6) + part * 8);
        if (e >= end) { u.x = 0u; u.y = 0u; }
        f32x2 f;
        f = __builtin_amdgcn_cvt_pk_f32_fp8(u.x, false); acc[0] += f.x; acc[1] += f.y;
        f = __builtin_amdgcn_cvt_pk_f32_fp8(u.x, true);  acc[2] += f.x; acc[3] += f.y;
        f = __builtin_amdgcn_cvt_pk_f32_fp8(u.y, false); acc[4] += f.x; acc[5] += f.y;
        f = __builtin_amdgcn_cvt_pk_f32_fp8(u.y, true);  acc[6] += f.x; acc[7] += f.y;
    }
#pragma unroll
    for (int off = 8; off <= 32; off <<= 1)
#pragma unroll
        for (int j = 0; j < 8; ++j)
            acc[j] += __shfl_xor(acc[j], off);

    if (slot == 0) {   // lanes 0..7 hold channels part*8 .. part*8+7
        float inv = __builtin_amdgcn_rcpf(fmaxf((float)(end - start), 1.0f));
        size_t bi = (size_t)row * HID_C + part * 8;
        ushort_t rr[8];
        *(uint4*)rr = *(const uint4*)(h1r + bi);
        float4 bb0 = *(const float4*)(b1 + part * 8);
        float4 bb1 = *(const float4*)(b1 + part * 8 + 4);
        ushort_t o[8];
        o[0] = f2bfu(fmaxf(acc[0] * inv + bfu2f(rr[0]) + bb0.x, 0.f));
        o[1] = f2bfu(fmaxf(acc[1] * inv + bfu2f(rr[1]) + bb0.y, 0.f));
        o[2] = f2bfu(fmaxf(acc[2] * inv + bfu2f(rr[2]) + bb0.z, 0.f));
        o[3] = f2bfu(fmaxf(acc[3] * inv + bfu2f(rr[3]) + bb0.w, 0.f));
        o[4] = f2bfu(fmaxf(acc[4] * inv + bfu2f(rr[4]) + bb1.x, 0.f));
        o[5] = f2bfu(fmaxf(acc[5] * inv + bfu2f(rr[5]) + bb1.y, 0.f));
        o[6] = f2bfu(fmaxf(acc[6] * inv + bfu2f(rr[6]) + bb1.z, 0.f));
        o[7] = f2bfu(fmaxf(acc[7] * inv + bfu2f(rr[7]) + bb1.w, 0.f));
        *(uint4*)(hid + bi) = *(const uint4*)o;
    }
}

// ================================================================ GEMM2 (MFMA): [h2l(fp8,stride64) | h2r(bf16)] = hid(bf16) @ [Wl2|Wr2]
__global__ __launch_bounds__(256) void k_gemm2(const ushort_t* __restrict__ hid,
                                               const ushort_t* __restrict__ Wt,  // [80][64] bf16
                                               uchar_t* __restrict__ h2l,
                                               ushort_t* __restrict__ h2r) {
    __shared__ ushort_t hs[64 * 72];
    __shared__ ushort_t wsm[80 * 72];
    const int t = threadIdx.x;
    const int row_base = blockIdx.x * 64;

    for (int i = t; i < 80 * 8; i += 256) {
        int n = i >> 3, seg = i & 7;
        uint4 v = *(const uint4*)(Wt + n * 64 + seg * 8);
        *(uint4*)(wsm + n * 72 + seg * 8) = v;
    }
    for (int i = t; i < 64 * 8; i += 256) {
        int row = i >> 3, seg = i & 7;
        int gr = row_base + row;
        uint4 v = make_uint4(0u, 0u, 0u, 0u);
        if (gr < N_NODES) v = *(const uint4*)(hid + (size_t)gr * HID_C + seg * 8);
        *(uint4*)(hs + row * 72 + seg * 8) = v;
    }
    __syncthreads();

    const int wv = t >> 6, lane = t & 63;
    const int m = lane & 15, quad = lane >> 4;
    const int m0 = wv * 16;

    bf16x8 a[2];
#pragma unroll
    for (int kk = 0; kk < 2; ++kk)
        a[kk] = *(const bf16x8*)(hs + (m0 + m) * 72 + kk * 32 + quad * 8);

    f32x4 acc[5];
#pragma unroll
    for (int nt = 0; nt < 5; ++nt) acc[nt] = (f32x4){0.f, 0.f, 0.f, 0.f};

#pragma unroll
    for (int nt = 0; nt < 5; ++nt) {
#pragma unroll
        for (int kk = 0; kk < 2; ++kk) {
            bf16x8 b = *(const bf16x8*)(wsm + (nt * 16 + m) * 72 + kk * 32 + quad * 8);
            acc[nt] = __builtin_amdgcn_mfma_f32_16x16x32_bf16(a[kk], b, acc[nt], 0, 0, 0);
        }
    }

    const int grow_base = row_base + m0 + quad * 4;
#pragma unroll
    for (int r = 0; r < 4; ++r) {
        int grow = grow_base + r;
        if (grow < N_NODES) {
#pragma unroll
            for (int nt = 0; nt < 5; ++nt) {
                int col = nt * 16 + m;
                float v = acc[nt][r];
                if (col < OUT_C) h2l[(size_t)grow * 64 + col] = f2fp8(v);
                else             h2r[(size_t)grow * OUT_C + (col - OUT_C)] = f2bfu(v);
            }
        }
    }
}

// ================================================================ agg2: 8-slot uint2 gather of fp8 h2l (40B in 64B stride)
// clean loop + masked remainder (parts 5..7 garbage stays confined); fused log_softmax
__global__ __launch_bounds__(256) void k_agg2(const int* __restrict__ rowptr, const int* __restrict__ csr,
                                              const uchar_t* __restrict__ h2l, const ushort_t* __restrict__ h2r,
                                              const float* __restrict__ b2, float* __restrict__ out) {
    int row = (blockIdx.x * 256 + threadIdx.x) >> 6;
    int lane = threadIdx.x & 63;
    if (row >= N_NODES) return;
    int start = rowptr[row];
    int end = rowptr[row + 1];
    const int slot = lane >> 3;
    const int part = lane & 7;
    float acc[8] = {0.f, 0.f, 0.f, 0.f, 0.f, 0.f, 0.f, 0.f};

    int base = start;
    for (; base + 8 <= end; base += 8) {
        int s = csr[base + slot];
        uint2 u = *(const uint2*)(h2l + ((size_t)s << 6) + part * 8);
        f32x2 f;
        f = __builtin_amdgcn_cvt_pk_f32_fp8(u.x, false); acc[0] += f.x; acc[1] += f.y;
        f = __builtin_amdgcn_cvt_pk_f32_fp8(u.x, true);  acc[2] += f.x; acc[3] += f.y;
        f = __builtin_amdgcn_cvt_pk_f32_fp8(u.y, false); acc[4] += f.x; acc[5] += f.y;
        f = __builtin_amdgcn_cvt_pk_f32_fp8(u.y, true);  acc[6] += f.x; acc[7] += f.y;
    }
    if (base < end) {
        int e = base + slot;
        int s = csr[min(e, end - 1)];
        uint2 u = *(const uint2*)(h2l + ((size_t)s << 6) + part * 8);
        if (e >= end) { u.x = 0u; u.y = 0u; }
        f32x2 f;
        f = __builtin_amdgcn_cvt_pk_f32_fp8(u.x, false); acc[0] += f.x; acc[1] += f.y;
        f = __builtin_amdgcn_cvt_pk_f32_fp8(u.x, true);  acc[2] += f.x; acc[3] += f.y;
        f = __builtin_amdgcn_cvt_pk_f32_fp8(u.y, false); acc[4] += f.x; acc[5] += f.y;
        f = __builtin_amdgcn_cvt_pk_f32_fp8(u.y, true);  acc[6] += f.x; acc[7] += f.y;
    }
#pragma unroll
    for (int off = 8; off <= 32; off <<= 1)
#pragma unroll
        for (int j = 0; j < 8; ++j)
            acc[j] += __shfl_xor(acc[j], off);

    // slot-0 lanes with part<5 hold channels part*8 .. part*8+7
    const bool fin = (slot == 0) && (part < 5);
    float inv = __builtin_amdgcn_rcpf(fmaxf((float)(end - start), 1.0f));
    float v[8];
    if (fin) {
        size_t bi = (size_t)row * OUT_C + part * 8;
        ushort_t rr[8];
        *(uint2*)&rr[0] = *(const uint2*)(h2r + bi);
        *(uint2*)&rr[4] = *(const uint2*)(h2r + bi + 4);
        float4 bb0 = *(const float4*)(b2 + part * 8);
        float4 bb1 = *(const float4*)(b2 + part * 8 + 4);
        v[0] = acc[0] * inv + bfu2f(rr[0]) + bb0.x;
        v[1] = acc[1] * inv + bfu2f(rr[1]) + bb0.y;
        v[2] = acc[2] * inv + bfu2f(rr[2]) + bb0.z;
        v[3] = acc[3] * inv + bfu2f(rr[3]) + bb0.w;
        v[4] = acc[4] * inv + bfu2f(rr[4]) + bb1.x;
        v[5] = acc[5] * inv + bfu2f(rr[5]) + bb1.y;
        v[6] = acc[6] * inv + bfu2f(rr[6]) + bb1.z;
        v[7] = acc[7] * inv + bfu2f(rr[7]) + bb1.w;
    } else {
#pragma unroll
        for (int j = 0; j < 8; ++j) v[j] = -1e30f;
    }
    // softmax stats within the 8-lane group (non-fin lanes compute garbage, never write)
    float pm = v[0];
#pragma unroll
    for (int j = 1; j < 8; ++j) pm = fmaxf(pm, v[j]);
#pragma unroll
    for (int off = 1; off <= 4; off <<= 1) pm = fmaxf(pm, __shfl_xor(pm, off));
    float es = 0.f;
#pragma unroll
    for (int j = 0; j < 8; ++j) es += expf(v[j] - pm);
#pragma unroll
    for (int off = 1; off <= 4; off <<= 1) es += __shfl_xor(es, off);
    float ls = logf(es);
    if (fin) {
        size_t bo = (size_t)row * OUT_C + part * 8;
        *(float4*)(out + bo) = make_float4(v[0] - pm - ls, v[1] - pm - ls, v[2] - pm - ls, v[3] - pm - ls);
        *(float4*)(out + bo + 4) = make_float4(v[4] - pm - ls, v[5] - pm - ls, v[6] - pm - ls, v[7] - pm - ls);
    }
}

// ----------------------------------------------------------------
extern "C" void kernel_launch(void* const* d_in, const int* in_sizes, int n_in,
                              void* d_out, int out_size, void* d_ws, size_t ws_size,
                              hipStream_t stream) {
    const float* x   = (const float*)d_in[0];
    const int*   ei  = (const int*)d_in[1];
    const float* Wl1 = (const float*)d_in[2];
    const float* b1  = (const float*)d_in[3];
    const float* Wr1 = (const float*)d_in[4];
    const float* Wl2 = (const float*)d_in[5];
    const float* b2  = (const float*)d_in[6];
    const float* Wr2 = (const float*)d_in[7];

    // ws layout (4B units): bucket int[196*9216] | bcur | rowptr[N+1] | csr[E] | [align16] |
    //   Wt1 bf16[128*128] | Wt2 bf16[80*64] | h1l fp8[N*64] | h1r bf16[N*64] | hid bf16[N*64] |
    //   h2l fp8[N*64] | h2r bf16[N*40]
    size_t u = 0;
    int*      bucket = (int*)d_ws;             u += (size_t)NBUCK * BCAP;
    int*      bcur   = (int*)d_ws + u;         u += NBUCK + 4;
    int*      rowptr = (int*)d_ws + u;         u += N_NODES + 1;
    int*      csr    = (int*)d_ws + u;         u += E_EDGES;
    u = (u + 3) & ~(size_t)3;                  // 16B align
    ushort_t* Wt1    = (ushort_t*)((int*)d_ws + u); u += 128 * 128 / 2;
    ushort_t* Wt2    = (ushort_t*)((int*)d_ws + u); u += 80 * 64 / 2;
    uchar_t*  h1l    = (uchar_t*)((int*)d_ws + u);  u += (size_t)N_NODES * HID_C / 4;
    ushort_t* h1r    = (ushort_t*)((int*)d_ws + u); u += (size_t)N_NODES * HID_C / 2;
    ushort_t* hid    = (ushort_t*)((int*)d_ws + u); u += (size_t)N_NODES * HID_C / 2;
    uchar_t*  h2l    = (uchar_t*)((int*)d_ws + u);  u += (size_t)N_NODES * 64 / 4;
    ushort_t* h2r    = (ushort_t*)((int*)d_ws + u); u += (size_t)N_NODES * OUT_C / 2;
    if (ws_size < u * 4) return;

    hipMemsetAsync(bcur, 0, NBUCK * sizeof(int), stream);

    const int* src = ei;
    const int* dst = ei + E_EDGES;

    k_prep<<<B1_GRID + 64, 256, 0, stream>>>(src, dst, bcur, bucket, Wl1, Wr1, Wl2, Wr2, Wt1, Wt2);
    k_csr_gemm1<<<NBUCK + GEMM1_GRID, 256, 0, stream>>>(bucket, bcur, rowptr, csr, x, Wt1, h1l, h1r);
    k_agg1<<<N_NODES / 4, 256, 0, stream>>>(rowptr, csr, h1l, h1r, b1, hid);
    k_gemm2<<<GEMM1_GRID, 256, 0, stream>>>(hid, Wt2, h2l, h2r);
    k_agg2<<<N_NODES / 4, 256, 0, stream>>>(rowptr, csr, h2l, h2r, b2, (float*)d_out);
}

// Round 11
// 257.802 us; speedup vs baseline: 1.2003x; 1.0252x over previous
//
#include <hip/hip_runtime.h>
#include <hip/hip_bf16.h>

#define N_NODES 100000
#define E_EDGES 1600000
#define IN_C 128
#define HID_C 64
#define OUT_C 40

#define NBUCK 196          // ceil(100000 / 512) buckets by dst>>9
#define BCAP 9216          // mean 8192 + 11 sigma
#define B1_EPT 16
#define B1_CHUNK (256 * B1_EPT)   // 4096 edges per block
#define B1_GRID ((E_EDGES + B1_CHUNK - 1) / B1_CHUNK)
#define GEMM1_GRID ((N_NODES + 63) / 64)

typedef unsigned short ushort_t;
typedef unsigned int uint_t;
typedef unsigned char uchar_t;
typedef __attribute__((ext_vector_type(8))) short bf16x8;
typedef __attribute__((ext_vector_type(4))) float f32x4;
typedef __attribute__((ext_vector_type(2))) float f32x2;

__device__ __forceinline__ float bfu2f(ushort_t u) {
    return __uint_as_float(((uint_t)u) << 16);
}
__device__ __forceinline__ ushort_t f2bfu(float f) {   // RNE
    uint_t u = __float_as_uint(f);
    return (ushort_t)((u + 0x7FFFu + ((u >> 16) & 1u)) >> 16);
}
__device__ __forceinline__ uchar_t f2fp8(float f) {    // e4m3 via HW cvt
    int p = __builtin_amdgcn_cvt_pk_fp8_f32(f, f, 0, false);
    return (uchar_t)(p & 0xff);
}

// ================================================================ K1: bucket (blocks 0..B1_GRID-1) || wprep (rest)
__global__ __launch_bounds__(256) void k_prep(const int* __restrict__ src, const int* __restrict__ dst,
                                              int* __restrict__ bcur, int* __restrict__ bucket,
                                              const float* __restrict__ Wl1, const float* __restrict__ Wr1,
                                              const float* __restrict__ Wl2, const float* __restrict__ Wr2,
                                              ushort_t* __restrict__ Wt1, ushort_t* __restrict__ Wt2) {
    __shared__ int cnt[NBUCK];
    __shared__ int base[NBUCK];
    const int t = threadIdx.x;

    if (blockIdx.x < B1_GRID) {
        // ---- bucketize edges by dst>>9 (packed: src | dlocal<<17)
        const int e0 = blockIdx.x * B1_CHUNK;
        for (int i = t; i < NBUCK; i += 256) cnt[i] = 0;
        __syncthreads();

        int myp[B1_EPT];
        int myb[B1_EPT];
#pragma unroll
        for (int j = 0; j < B1_EPT; ++j) {
            int e = e0 + t + j * 256;
            if (e < E_EDGES) {
                int d = dst[e];
                myp[j] = src[e] | ((d & 511) << 17);
                myb[j] = d >> 9;
                atomicAdd(&cnt[myb[j]], 1);
            } else {
                myb[j] = -1;
            }
        }
        __syncthreads();
        for (int i = t; i < NBUCK; i += 256) {
            base[i] = atomicAdd(&bcur[i], cnt[i]);
            cnt[i] = 0;
        }
        __syncthreads();
#pragma unroll
        for (int j = 0; j < B1_EPT; ++j) {
            if (myb[j] >= 0) {
                int b = myb[j];
                int loc = atomicAdd(&cnt[b], 1);
                int pos = base[b] + loc;
                if (pos < BCAP) bucket[(size_t)b * BCAP + pos] = myp[j];
            }
        }
    } else {
        // ---- weight prep: bf16, transposed, l|r concatenated
        int i = (blockIdx.x - B1_GRID) * 256 + t;
        if (i < 128 * 128) {
            int n = i >> 7, k = i & 127;
            float v = (n < 64) ? Wl1[k * 64 + n] : Wr1[k * 64 + (n - 64)];
            Wt1[n * 128 + k] = f2bfu(v);
        }
        if (i < 80 * 64) {
            int n = i >> 6, k = i & 63;
            float v = (n < 40) ? Wl2[k * 40 + n] : Wr2[k * 40 + (n - 40)];
            Wt2[n * 64 + k] = f2bfu(v);
        }
    }
}

// ================================================================ K2: csr (blocks 0..NBUCK-1) || gemm1 (rest)
struct SmemCsr {
    int red[256];
    int hist[512];
    int sc[2][512];
    int cur[512];
    int csrbuf[BCAP];
};
struct SmemGemm1 {
    ushort_t xs[64 * 136];
    ushort_t wsm[128 * 136];
};
union SmemK2 {
    SmemCsr c;
    SmemGemm1 g;
};

__global__ __launch_bounds__(256) void k_csr_gemm1(const int* __restrict__ bucket, const int* __restrict__ bcur,
                                                   int* __restrict__ rowptr, int* __restrict__ csr,
                                                   const float* __restrict__ x, const ushort_t* __restrict__ Wt,
                                                   uchar_t* __restrict__ h1l, ushort_t* __restrict__ h1r) {
    __shared__ SmemK2 sm;
    const int t = threadIdx.x;

    if (blockIdx.x < NBUCK) {
        // ---- per-bucket counting sort -> rowptr slice + csr slice (inline exclusive base)
        const int b = blockIdx.x;
        const int n0 = b << 9;
        const int nb = min(512, N_NODES - n0);
        const int sz = min(bcur[b], BCAP);
        const int* bdata = bucket + (size_t)b * BCAP;

        int v = (t < b) ? min(bcur[t], BCAP) : 0;   // NBUCK=196 <= 256
        sm.c.red[t] = v;
        __syncthreads();
        for (int off = 128; off > 0; off >>= 1) {
            if (t < off) sm.c.red[t] += sm.c.red[t + off];
            __syncthreads();
        }
        const int cbase = sm.c.red[0];

        for (int i = t; i < 512; i += 256) sm.c.hist[i] = 0;
        __syncthreads();
        for (int i = t; i < sz; i += 256) {
            int p = bdata[i];
            atomicAdd(&sm.c.hist[p >> 17], 1);
        }
        __syncthreads();
        for (int i = t; i < 512; i += 256) sm.c.sc[0][i] = sm.c.hist[i];
        __syncthreads();
        int pp = 0;
        for (int off = 1; off < 512; off <<= 1) {
            for (int i = t; i < 512; i += 256)
                sm.c.sc[1 - pp][i] = sm.c.sc[pp][i] + ((i >= off) ? sm.c.sc[pp][i - off] : 0);
            __syncthreads();
            pp ^= 1;
        }
        for (int i = t; i < 512; i += 256) {
            int exc = sm.c.sc[pp][i] - sm.c.hist[i];
            sm.c.cur[i] = exc;
            if (i < nb) rowptr[n0 + i] = cbase + exc;
        }
        __syncthreads();
        for (int i = t; i < sz; i += 256) {
            int p = bdata[i];
            int pos = atomicAdd(&sm.c.cur[p >> 17], 1);
            sm.c.csrbuf[pos] = p & 0x1FFFF;
        }
        __syncthreads();
        for (int i = t; i < sz; i += 256)
            csr[cbase + i] = sm.c.csrbuf[i];
        if (b == NBUCK - 1 && t == 0) rowptr[N_NODES] = cbase + sz;
    } else {
        // ---- GEMM1 (MFMA): [h1l(fp8) | h1r(bf16)] = x @ [Wl1|Wr1]
        const int row_base = (blockIdx.x - NBUCK) * 64;

        for (int i = t; i < 128 * 16; i += 256) {
            int n = i >> 4, seg = i & 15;
            uint4 v = *(const uint4*)(Wt + n * 128 + seg * 8);
            *(uint4*)(sm.g.wsm + n * 136 + seg * 8) = v;
        }
        for (int i = t; i < 64 * 32; i += 256) {
            int row = i >> 5, seg = i & 31;
            int gr = row_base + row;
            float4 v = make_float4(0.f, 0.f, 0.f, 0.f);
            if (gr < N_NODES) v = *(const float4*)(x + (size_t)gr * IN_C + seg * 4);
            ushort4 u;
            u.x = f2bfu(v.x); u.y = f2bfu(v.y); u.z = f2bfu(v.z); u.w = f2bfu(v.w);
            *(ushort4*)(sm.g.xs + row * 136 + seg * 4) = u;
        }
        __syncthreads();

        const int wv = t >> 6, lane = t & 63;
        const int m = lane & 15, quad = lane >> 4;
        const int m0 = wv * 16;

        bf16x8 a[4];
#pragma unroll
        for (int kk = 0; kk < 4; ++kk)
            a[kk] = *(const bf16x8*)(sm.g.xs + (m0 + m) * 136 + kk * 32 + quad * 8);

        f32x4 acc[8];
#pragma unroll
        for (int nt = 0; nt < 8; ++nt) acc[nt] = (f32x4){0.f, 0.f, 0.f, 0.f};

#pragma unroll
        for (int nt = 0; nt < 8; ++nt) {
#pragma unroll
            for (int kk = 0; kk < 4; ++kk) {
                bf16x8 b = *(const bf16x8*)(sm.g.wsm + (nt * 16 + m) * 136 + kk * 32 + quad * 8);
                acc[nt] = __builtin_amdgcn_mfma_f32_16x16x32_bf16(a[kk], b, acc[nt], 0, 0, 0);
            }
        }

        const int grow_base = row_base + m0 + quad * 4;
#pragma unroll
        for (int r = 0; r < 4; ++r) {
            int grow = grow_base + r;
            if (grow < N_NODES) {
#pragma unroll
                for (int nt = 0; nt < 4; ++nt)
                    h1l[(size_t)grow * HID_C + nt * 16 + m] = f2fp8(acc[nt][r]);
#pragma unroll
                for (int nt = 4; nt < 8; ++nt)
                    h1r[(size_t)grow * HID_C + (nt - 4) * 16 + m] = f2bfu(acc[nt][r]);
            }
        }
    }
}

// ================================================================ agg1: 8-slot uint2 gather of fp8 h1l (64B rows)
// packed-f32 accumulation; static-xor reduce (pk adds); root h1r bf16; writes hid bf16
__global__ __launch_bounds__(256) void k_agg1(const int* __restrict__ rowptr, const int* __restrict__ csr,
                                              const uchar_t* __restrict__ h1l, const ushort_t* __restrict__ h1r,
                                              const float* __restrict__ b1, ushort_t* __restrict__ hid) {
    int row = (blockIdx.x * 256 + threadIdx.x) >> 6;
    int lane = threadIdx.x & 63;
    if (row >= N_NODES) return;
    int start = rowptr[row];
    int end = rowptr[row + 1];
    const int slot = lane >> 3;
    const int part = lane & 7;
    f32x2 acc[4];
#pragma unroll
    for (int j = 0; j < 4; ++j) acc[j] = (f32x2){0.f, 0.f};

    int base = start;
    for (; base + 8 <= end; base += 8) {
        int s = csr[base + slot];
        uint2 u = *(const uint2*)(h1l + ((size_t)s << 6) + part * 8);
        acc[0] += __builtin_amdgcn_cvt_pk_f32_fp8(u.x, false);
        acc[1] += __builtin_amdgcn_cvt_pk_f32_fp8(u.x, true);
        acc[2] += __builtin_amdgcn_cvt_pk_f32_fp8(u.y, false);
        acc[3] += __builtin_amdgcn_cvt_pk_f32_fp8(u.y, true);
    }
    if (base < end) {
        int e = base + slot;
        int s = csr[min(e, end - 1)];
        uint2 u = *(const uint2*)(h1l + ((size_t)s << 6) + part * 8);
        if (e >= end) { u.x = 0u; u.y = 0u; }
        acc[0] += __builtin_amdgcn_cvt_pk_f32_fp8(u.x, false);
        acc[1] += __builtin_amdgcn_cvt_pk_f32_fp8(u.x, true);
        acc[2] += __builtin_amdgcn_cvt_pk_f32_fp8(u.y, false);
        acc[3] += __builtin_amdgcn_cvt_pk_f32_fp8(u.y, true);
    }
#pragma unroll
    for (int off = 8; off <= 32; off <<= 1) {
#pragma unroll
        for (int j = 0; j < 4; ++j) {
            f32x2 tt;
            tt.x = __shfl_xor(acc[j].x, off);
            tt.y = __shfl_xor(acc[j].y, off);
            acc[j] += tt;
        }
    }

    if (slot == 0) {   // lanes 0..7 hold channels part*8 .. part*8+7
        float inv = __builtin_amdgcn_rcpf(fmaxf((float)(end - start), 1.0f));
        size_t bi = (size_t)row * HID_C + part * 8;
        ushort_t rr[8];
        *(uint4*)rr = *(const uint4*)(h1r + bi);
        float4 bb0 = *(const float4*)(b1 + part * 8);
        float4 bb1 = *(const float4*)(b1 + part * 8 + 4);
        ushort_t o[8];
        o[0] = f2bfu(fmaxf(acc[0].x * inv + bfu2f(rr[0]) + bb0.x, 0.f));
        o[1] = f2bfu(fmaxf(acc[0].y * inv + bfu2f(rr[1]) + bb0.y, 0.f));
        o[2] = f2bfu(fmaxf(acc[1].x * inv + bfu2f(rr[2]) + bb0.z, 0.f));
        o[3] = f2bfu(fmaxf(acc[1].y * inv + bfu2f(rr[3]) + bb0.w, 0.f));
        o[4] = f2bfu(fmaxf(acc[2].x * inv + bfu2f(rr[4]) + bb1.x, 0.f));
        o[5] = f2bfu(fmaxf(acc[2].y * inv + bfu2f(rr[5]) + bb1.y, 0.f));
        o[6] = f2bfu(fmaxf(acc[3].x * inv + bfu2f(rr[6]) + bb1.z, 0.f));
        o[7] = f2bfu(fmaxf(acc[3].y * inv + bfu2f(rr[7]) + bb1.w, 0.f));
        *(uint4*)(hid + bi) = *(const uint4*)o;
    }
}

// ================================================================ GEMM2 (MFMA): [h2l(fp8,stride64) | h2r(bf16)] = hid(bf16) @ [Wl2|Wr2]
__global__ __launch_bounds__(256) void k_gemm2(const ushort_t* __restrict__ hid,
                                               const ushort_t* __restrict__ Wt,  // [80][64] bf16
                                               uchar_t* __restrict__ h2l,
                                               ushort_t* __restrict__ h2r) {
    __shared__ ushort_t hs[64 * 72];
    __shared__ ushort_t wsm[80 * 72];
    const int t = threadIdx.x;
    const int row_base = blockIdx.x * 64;

    for (int i = t; i < 80 * 8; i += 256) {
        int n = i >> 3, seg = i & 7;
        uint4 v = *(const uint4*)(Wt + n * 64 + seg * 8);
        *(uint4*)(wsm + n * 72 + seg * 8) = v;
    }
    for (int i = t; i < 64 * 8; i += 256) {
        int row = i >> 3, seg = i & 7;
        int gr = row_base + row;
        uint4 v = make_uint4(0u, 0u, 0u, 0u);
        if (gr < N_NODES) v = *(const uint4*)(hid + (size_t)gr * HID_C + seg * 8);
        *(uint4*)(hs + row * 72 + seg * 8) = v;
    }
    __syncthreads();

    const int wv = t >> 6, lane = t & 63;
    const int m = lane & 15, quad = lane >> 4;
    const int m0 = wv * 16;

    bf16x8 a[2];
#pragma unroll
    for (int kk = 0; kk < 2; ++kk)
        a[kk] = *(const bf16x8*)(hs + (m0 + m) * 72 + kk * 32 + quad * 8);

    f32x4 acc[5];
#pragma unroll
    for (int nt = 0; nt < 5; ++nt) acc[nt] = (f32x4){0.f, 0.f, 0.f, 0.f};

#pragma unroll
    for (int nt = 0; nt < 5; ++nt) {
#pragma unroll
        for (int kk = 0; kk < 2; ++kk) {
            bf16x8 b = *(const bf16x8*)(wsm + (nt * 16 + m) * 72 + kk * 32 + quad * 8);
            acc[nt] = __builtin_amdgcn_mfma_f32_16x16x32_bf16(a[kk], b, acc[nt], 0, 0, 0);
        }
    }

    const int grow_base = row_base + m0 + quad * 4;
#pragma unroll
    for (int r = 0; r < 4; ++r) {
        int grow = grow_base + r;
        if (grow < N_NODES) {
#pragma unroll
            for (int nt = 0; nt < 5; ++nt) {
                int col = nt * 16 + m;
                float v = acc[nt][r];
                if (col < OUT_C) h2l[(size_t)grow * 64 + col] = f2fp8(v);
                else             h2r[(size_t)grow * OUT_C + (col - OUT_C)] = f2bfu(v);
            }
        }
    }
}

// ================================================================ agg2: 8-slot uint2 gather of fp8 h2l (40B in 64B stride)
// packed-f32 accumulation; static-xor reduce (pk adds); native-exp log_softmax
__global__ __launch_bounds__(256) void k_agg2(const int* __restrict__ rowptr, const int* __restrict__ csr,
                                              const uchar_t* __restrict__ h2l, const ushort_t* __restrict__ h2r,
                                              const float* __restrict__ b2, float* __restrict__ out) {
    int row = (blockIdx.x * 256 + threadIdx.x) >> 6;
    int lane = threadIdx.x & 63;
    if (row >= N_NODES) return;
    int start = rowptr[row];
    int end = rowptr[row + 1];
    const int slot = lane >> 3;
    const int part = lane & 7;
    f32x2 acc[4];
#pragma unroll
    for (int j = 0; j < 4; ++j) acc[j] = (f32x2){0.f, 0.f};

    int base = start;
    for (; base + 8 <= end; base += 8) {
        int s = csr[base + slot];
        uint2 u = *(const uint2*)(h2l + ((size_t)s << 6) + part * 8);
        acc[0] += __builtin_amdgcn_cvt_pk_f32_fp8(u.x, false);
        acc[1] += __builtin_amdgcn_cvt_pk_f32_fp8(u.x, true);
        acc[2] += __builtin_amdgcn_cvt_pk_f32_fp8(u.y, false);
        acc[3] += __builtin_amdgcn_cvt_pk_f32_fp8(u.y, true);
    }
    if (base < end) {
        int e = base + slot;
        int s = csr[min(e, end - 1)];
        uint2 u = *(const uint2*)(h2l + ((size_t)s << 6) + part * 8);
        if (e >= end) { u.x = 0u; u.y = 0u; }
        acc[0] += __builtin_amdgcn_cvt_pk_f32_fp8(u.x, false);
        acc[1] += __builtin_amdgcn_cvt_pk_f32_fp8(u.x, true);
        acc[2] += __builtin_amdgcn_cvt_pk_f32_fp8(u.y, false);
        acc[3] += __builtin_amdgcn_cvt_pk_f32_fp8(u.y, true);
    }
#pragma unroll
    for (int off = 8; off <= 32; off <<= 1) {
#pragma unroll
        for (int j = 0; j < 4; ++j) {
            f32x2 tt;
            tt.x = __shfl_xor(acc[j].x, off);
            tt.y = __shfl_xor(acc[j].y, off);
            acc[j] += tt;
        }
    }

    // slot-0 lanes with part<5 hold channels part*8 .. part*8+7
    const bool fin = (slot == 0) && (part < 5);
    float inv = __builtin_amdgcn_rcpf(fmaxf((float)(end - start), 1.0f));
    f32x2 v2[4];
    if (fin) {
        size_t bi = (size_t)row * OUT_C + part * 8;
        ushort_t rr[8];
        *(uint2*)&rr[0] = *(const uint2*)(h2r + bi);
        *(uint2*)&rr[4] = *(const uint2*)(h2r + bi + 4);
        float4 bb0 = *(const float4*)(b2 + part * 8);
        float4 bb1 = *(const float4*)(b2 + part * 8 + 4);
        v2[0] = (f32x2){acc[0].x * inv + bfu2f(rr[0]) + bb0.x, acc[0].y * inv + bfu2f(rr[1]) + bb0.y};
        v2[1] = (f32x2){acc[1].x * inv + bfu2f(rr[2]) + bb0.z, acc[1].y * inv + bfu2f(rr[3]) + bb0.w};
        v2[2] = (f32x2){acc[2].x * inv + bfu2f(rr[4]) + bb1.x, acc[2].y * inv + bfu2f(rr[5]) + bb1.y};
        v2[3] = (f32x2){acc[3].x * inv + bfu2f(rr[6]) + bb1.z, acc[3].y * inv + bfu2f(rr[7]) + bb1.w};
    } else {
#pragma unroll
        for (int j = 0; j < 4; ++j) v2[j] = (f32x2){-1e30f, -1e30f};
    }
    // softmax stats within the 8-lane group (non-fin lanes compute garbage, never write)
    f32x2 m2;
    m2.x = fmaxf(fmaxf(v2[0].x, v2[1].x), fmaxf(v2[2].x, v2[3].x));
    m2.y = fmaxf(fmaxf(v2[0].y, v2[1].y), fmaxf(v2[2].y, v2[3].y));
    float pm = fmaxf(m2.x, m2.y);
#pragma unroll
    for (int off = 1; off <= 4; off <<= 1) pm = fmaxf(pm, __shfl_xor(pm, off));
    float es = 0.f;
#pragma unroll
    for (int j = 0; j < 4; ++j) {
        es += __expf(v2[j].x - pm);
        es += __expf(v2[j].y - pm);
    }
#pragma unroll
    for (int off = 1; off <= 4; off <<= 1) es += __shfl_xor(es, off);
    float ls = __logf(es);
    if (fin) {
        size_t bo = (size_t)row * OUT_C + part * 8;
        *(float4*)(out + bo) = make_float4(v2[0].x - pm - ls, v2[0].y - pm - ls,
                                           v2[1].x - pm - ls, v2[1].y - pm - ls);
        *(float4*)(out + bo + 4) = make_float4(v2[2].x - pm - ls, v2[2].y - pm - ls,
                                               v2[3].x - pm - ls, v2[3].y - pm - ls);
    }
}

// ----------------------------------------------------------------
extern "C" void kernel_launch(void* const* d_in, const int* in_sizes, int n_in,
                              void* d_out, int out_size, void* d_ws, size_t ws_size,
                              hipStream_t stream) {
    const float* x   = (const float*)d_in[0];
    const int*   ei  = (const int*)d_in[1];
    const float* Wl1 = (const float*)d_in[2];
    const float* b1  = (const float*)d_in[3];
    const float* Wr1 = (const float*)d_in[4];
    const float* Wl2 = (const float*)d_in[5];
    const float* b2  = (const float*)d_in[6];
    const float* Wr2 = (const float*)d_in[7];

    // ws layout (4B units): bucket int[196*9216] | bcur | rowptr[N+1] | csr[E] | [align16] |
    //   Wt1 bf16[128*128] | Wt2 bf16[80*64] | h1l fp8[N*64] | h1r bf16[N*64] | hid bf16[N*64] |
    //   h2l fp8[N*64] | h2r bf16[N*40]
    size_t u = 0;
    int*      bucket = (int*)d_ws;             u += (size_t)NBUCK * BCAP;
    int*      bcur   = (int*)d_ws + u;         u += NBUCK + 4;
    int*      rowptr = (int*)d_ws + u;         u += N_NODES + 1;
    int*      csr    = (int*)d_ws + u;         u += E_EDGES;
    u = (u + 3) & ~(size_t)3;                  // 16B align
    ushort_t* Wt1    = (ushort_t*)((int*)d_ws + u); u += 128 * 128 / 2;
    ushort_t* Wt2    = (ushort_t*)((int*)d_ws + u); u += 80 * 64 / 2;
    uchar_t*  h1l    = (uchar_t*)((int*)d_ws + u);  u += (size_t)N_NODES * HID_C / 4;
    ushort_t* h1r    = (ushort_t*)((int*)d_ws + u); u += (size_t)N_NODES * HID_C / 2;
    ushort_t* hid    = (ushort_t*)((int*)d_ws + u); u += (size_t)N_NODES * HID_C / 2;
    uchar_t*  h2l    = (uchar_t*)((int*)d_ws + u);  u += (size_t)N_NODES * 64 / 4;
    ushort_t* h2r    = (ushort_t*)((int*)d_ws + u); u += (size_t)N_NODES * OUT_C / 2;
    if (ws_size < u * 4) return;

    hipMemsetAsync(bcur, 0, NBUCK * sizeof(int), stream);

    const int* src = ei;
    const int* dst = ei + E_EDGES;

    k_prep<<<B1_GRID + 64, 256, 0, stream>>>(src, dst, bcur, bucket, Wl1, Wr1, Wl2, Wr2, Wt1, Wt2);
    k_csr_gemm1<<<NBUCK + GEMM1_GRID, 256, 0, stream>>>(bucket, bcur, rowptr, csr, x, Wt1, h1l, h1r);
    k_agg1<<<N_NODES / 4, 256, 0, stream>>>(rowptr, csr, h1l, h1r, b1, hid);
    k_gemm2<<<GEMM1_GRID, 256, 0, stream>>>(hid, Wt2, h2l, h2r);
    k_agg2<<<N_NODES / 4, 256, 0, stream>>>(rowptr, csr, h2l, h2r, b2, (float*)d_out);
}

// Round 12
// 256.999 us; speedup vs baseline: 1.2041x; 1.0031x over previous
//
#include <hip/hip_runtime.h>
#include <hip/hip_bf16.h>

#define N_NODES 100000
#define E_EDGES 1600000
#define IN_C 128
#define HID_C 64
#define OUT_C 40

#define NBUCK 196          // ceil(100000 / 512) buckets by dst>>9
#define BCAP 9216          // mean 8192 + 11 sigma
#define B1_EPT 16
#define B1_CHUNK (256 * B1_EPT)   // 4096 edges per block
#define B1_GRID ((E_EDGES + B1_CHUNK - 1) / B1_CHUNK)
#define TILE_GRID ((N_NODES + 63) / 64)

typedef unsigned short ushort_t;
typedef unsigned int uint_t;
typedef unsigned char uchar_t;
typedef __attribute__((ext_vector_type(8))) short bf16x8;
typedef __attribute__((ext_vector_type(4))) float f32x4;
typedef __attribute__((ext_vector_type(2))) float f32x2;

__device__ __forceinline__ float bfu2f(ushort_t u) {
    return __uint_as_float(((uint_t)u) << 16);
}
__device__ __forceinline__ ushort_t f2bfu(float f) {   // RNE
    uint_t u = __float_as_uint(f);
    return (ushort_t)((u + 0x7FFFu + ((u >> 16) & 1u)) >> 16);
}
__device__ __forceinline__ uchar_t f2fp8(float f) {    // e4m3 via HW cvt
    int p = __builtin_amdgcn_cvt_pk_fp8_f32(f, f, 0, false);
    return (uchar_t)(p & 0xff);
}

// ================================================================ K1: bucket (blocks 0..B1_GRID-1) || wprep (rest)
__global__ __launch_bounds__(256) void k_prep(const int* __restrict__ src, const int* __restrict__ dst,
                                              int* __restrict__ bcur, int* __restrict__ bucket,
                                              const float* __restrict__ Wl1, const float* __restrict__ Wr1,
                                              const float* __restrict__ Wl2, const float* __restrict__ Wr2,
                                              ushort_t* __restrict__ Wt1, ushort_t* __restrict__ Wt2) {
    __shared__ int cnt[NBUCK];
    __shared__ int base[NBUCK];
    const int t = threadIdx.x;

    if (blockIdx.x < B1_GRID) {
        // ---- bucketize edges by dst>>9 (packed: src | dlocal<<17)
        const int e0 = blockIdx.x * B1_CHUNK;
        for (int i = t; i < NBUCK; i += 256) cnt[i] = 0;
        __syncthreads();

        int myp[B1_EPT];
        int myb[B1_EPT];
#pragma unroll
        for (int j = 0; j < B1_EPT; ++j) {
            int e = e0 + t + j * 256;
            if (e < E_EDGES) {
                int d = dst[e];
                myp[j] = src[e] | ((d & 511) << 17);
                myb[j] = d >> 9;
                atomicAdd(&cnt[myb[j]], 1);
            } else {
                myb[j] = -1;
            }
        }
        __syncthreads();
        for (int i = t; i < NBUCK; i += 256) {
            base[i] = atomicAdd(&bcur[i], cnt[i]);
            cnt[i] = 0;
        }
        __syncthreads();
#pragma unroll
        for (int j = 0; j < B1_EPT; ++j) {
            if (myb[j] >= 0) {
                int b = myb[j];
                int loc = atomicAdd(&cnt[b], 1);
                int pos = base[b] + loc;
                if (pos < BCAP) bucket[(size_t)b * BCAP + pos] = myp[j];
            }
        }
    } else {
        // ---- weight prep: bf16, transposed, l|r concatenated
        int i = (blockIdx.x - B1_GRID) * 256 + t;
        if (i < 128 * 128) {
            int n = i >> 7, k = i & 127;
            float v = (n < 64) ? Wl1[k * 64 + n] : Wr1[k * 64 + (n - 64)];
            Wt1[n * 128 + k] = f2bfu(v);
        }
        if (i < 80 * 64) {
            int n = i >> 6, k = i & 63;
            float v = (n < 40) ? Wl2[k * 40 + n] : Wr2[k * 40 + (n - 40)];
            Wt2[n * 64 + k] = f2bfu(v);
        }
    }
}

// ================================================================ K2: csr (blocks 0..NBUCK-1) || gemm1 (rest)
struct SmemCsr {
    int red[256];
    int hist[512];
    int sc[2][512];
    int cur[512];
    int csrbuf[BCAP];
};
struct SmemGemm1 {
    ushort_t xs[64 * 136];
    ushort_t wsm[128 * 136];
};
union SmemK2 {
    SmemCsr c;
    SmemGemm1 g;
};

__global__ __launch_bounds__(256) void k_csr_gemm1(const int* __restrict__ bucket, const int* __restrict__ bcur,
                                                   int* __restrict__ rowptr, int* __restrict__ csr,
                                                   const float* __restrict__ x, const ushort_t* __restrict__ Wt,
                                                   uchar_t* __restrict__ h1l, ushort_t* __restrict__ h1r) {
    __shared__ SmemK2 sm;
    const int t = threadIdx.x;

    if (blockIdx.x < NBUCK) {
        // ---- per-bucket counting sort -> rowptr slice + csr slice (csr stores BYTE offsets s*64)
        const int b = blockIdx.x;
        const int n0 = b << 9;
        const int nb = min(512, N_NODES - n0);
        const int sz = min(bcur[b], BCAP);
        const int* bdata = bucket + (size_t)b * BCAP;

        int v = (t < b) ? min(bcur[t], BCAP) : 0;   // NBUCK=196 <= 256
        sm.c.red[t] = v;
        __syncthreads();
        for (int off = 128; off > 0; off >>= 1) {
            if (t < off) sm.c.red[t] += sm.c.red[t + off];
            __syncthreads();
        }
        const int cbase = sm.c.red[0];

        for (int i = t; i < 512; i += 256) sm.c.hist[i] = 0;
        __syncthreads();
        for (int i = t; i < sz; i += 256) {
            int p = bdata[i];
            atomicAdd(&sm.c.hist[p >> 17], 1);
        }
        __syncthreads();
        for (int i = t; i < 512; i += 256) sm.c.sc[0][i] = sm.c.hist[i];
        __syncthreads();
        int pp = 0;
        for (int off = 1; off < 512; off <<= 1) {
            for (int i = t; i < 512; i += 256)
                sm.c.sc[1 - pp][i] = sm.c.sc[pp][i] + ((i >= off) ? sm.c.sc[pp][i - off] : 0);
            __syncthreads();
            pp ^= 1;
        }
        for (int i = t; i < 512; i += 256) {
            int exc = sm.c.sc[pp][i] - sm.c.hist[i];
            sm.c.cur[i] = exc;
            if (i < nb) rowptr[n0 + i] = cbase + exc;
        }
        __syncthreads();
        for (int i = t; i < sz; i += 256) {
            int p = bdata[i];
            int pos = atomicAdd(&sm.c.cur[p >> 17], 1);
            sm.c.csrbuf[pos] = (p & 0x1FFFF) << 6;   // byte offset into 64B-stride feature rows
        }
        __syncthreads();
        for (int i = t; i < sz; i += 256)
            csr[cbase + i] = sm.c.csrbuf[i];
        if (b == NBUCK - 1 && t == 0) rowptr[N_NODES] = cbase + sz;
    } else {
        // ---- GEMM1 (MFMA): [h1l(fp8) | h1r(bf16)] = x @ [Wl1|Wr1]
        const int row_base = (blockIdx.x - NBUCK) * 64;

        for (int i = t; i < 128 * 16; i += 256) {
            int n = i >> 4, seg = i & 15;
            uint4 v = *(const uint4*)(Wt + n * 128 + seg * 8);
            *(uint4*)(sm.g.wsm + n * 136 + seg * 8) = v;
        }
        for (int i = t; i < 64 * 32; i += 256) {
            int row = i >> 5, seg = i & 31;
            int gr = row_base + row;
            float4 v = make_float4(0.f, 0.f, 0.f, 0.f);
            if (gr < N_NODES) v = *(const float4*)(x + (size_t)gr * IN_C + seg * 4);
            ushort4 u;
            u.x = f2bfu(v.x); u.y = f2bfu(v.y); u.z = f2bfu(v.z); u.w = f2bfu(v.w);
            *(ushort4*)(sm.g.xs + row * 136 + seg * 4) = u;
        }
        __syncthreads();

        const int wv = t >> 6, lane = t & 63;
        const int m = lane & 15, quad = lane >> 4;
        const int m0 = wv * 16;

        bf16x8 a[4];
#pragma unroll
        for (int kk = 0; kk < 4; ++kk)
            a[kk] = *(const bf16x8*)(sm.g.xs + (m0 + m) * 136 + kk * 32 + quad * 8);

        f32x4 acc[8];
#pragma unroll
        for (int nt = 0; nt < 8; ++nt) acc[nt] = (f32x4){0.f, 0.f, 0.f, 0.f};

#pragma unroll
        for (int nt = 0; nt < 8; ++nt) {
#pragma unroll
            for (int kk = 0; kk < 4; ++kk) {
                bf16x8 b = *(const bf16x8*)(sm.g.wsm + (nt * 16 + m) * 136 + kk * 32 + quad * 8);
                acc[nt] = __builtin_amdgcn_mfma_f32_16x16x32_bf16(a[kk], b, acc[nt], 0, 0, 0);
            }
        }

        const int grow_base = row_base + m0 + quad * 4;
#pragma unroll
        for (int r = 0; r < 4; ++r) {
            int grow = grow_base + r;
            if (grow < N_NODES) {
#pragma unroll
                for (int nt = 0; nt < 4; ++nt)
                    h1l[(size_t)grow * HID_C + nt * 16 + m] = f2fp8(acc[nt][r]);
#pragma unroll
                for (int nt = 4; nt < 8; ++nt)
                    h1r[(size_t)grow * HID_C + (nt - 4) * 16 + m] = f2bfu(acc[nt][r]);
            }
        }
    }
}

// ================================================================ K3: fused agg1 + gemm2
// Phase A: 4 waves x 16 serial rows: 8-slot fp8 gather (csr byte-offsets), relu(mean+root+b1) -> LDS bf16 tile
// Phase B: gemm2 MFMA from LDS: [h2l(fp8,stride64) | h2r(bf16)] = hid @ [Wl2|Wr2]
__global__ __launch_bounds__(256) void k_agg1_gemm2(const int* __restrict__ rowptr, const int* __restrict__ csr,
                                                    const uchar_t* __restrict__ h1l, const ushort_t* __restrict__ h1r,
                                                    const float* __restrict__ b1, const ushort_t* __restrict__ Wt,
                                                    uchar_t* __restrict__ h2l, ushort_t* __restrict__ h2r) {
    __shared__ ushort_t hs[64 * 72];     // hid tile, bf16
    __shared__ ushort_t wsm[80 * 72];    // Wt2
    const int t = threadIdx.x;
    const int row_base = blockIdx.x * 64;
    const int wv = t >> 6, lane = t & 63;
    const int slot = lane >> 3;
    const int part = lane & 7;

    // stage Wt2 (consumed after the phase-boundary syncthreads)
    for (int i = t; i < 80 * 8; i += 256) {
        int n = i >> 3, seg = i & 7;
        uint4 v = *(const uint4*)(Wt + n * 64 + seg * 8);
        *(uint4*)(wsm + n * 72 + seg * 8) = v;
    }

    // ---- phase A: aggregate 16 rows per wave
    float4 bb0, bb1;
    if (slot == 0) {
        bb0 = *(const float4*)(b1 + part * 8);
        bb1 = *(const float4*)(b1 + part * 8 + 4);
    }
    for (int r16 = 0; r16 < 16; ++r16) {
        int lrow = wv * 16 + r16;
        int row = row_base + lrow;
        if (row < N_NODES) {
            int2 rp = *(const int2*)(rowptr + row);
            int start = rp.x, end = rp.y;
            f32x2 acc[4];
#pragma unroll
            for (int j = 0; j < 4; ++j) acc[j] = (f32x2){0.f, 0.f};

            int base = start;
            for (; base + 8 <= end; base += 8) {
                int s = csr[base + slot];                       // byte offset
                uint2 u = *(const uint2*)(h1l + s + part * 8);
                acc[0] += __builtin_amdgcn_cvt_pk_f32_fp8(u.x, false);
                acc[1] += __builtin_amdgcn_cvt_pk_f32_fp8(u.x, true);
                acc[2] += __builtin_amdgcn_cvt_pk_f32_fp8(u.y, false);
                acc[3] += __builtin_amdgcn_cvt_pk_f32_fp8(u.y, true);
            }
            if (base < end) {
                int e = base + slot;
                int s = csr[min(e, end - 1)];
                uint2 u = *(const uint2*)(h1l + s + part * 8);
                if (e >= end) { u.x = 0u; u.y = 0u; }
                acc[0] += __builtin_amdgcn_cvt_pk_f32_fp8(u.x, false);
                acc[1] += __builtin_amdgcn_cvt_pk_f32_fp8(u.x, true);
                acc[2] += __builtin_amdgcn_cvt_pk_f32_fp8(u.y, false);
                acc[3] += __builtin_amdgcn_cvt_pk_f32_fp8(u.y, true);
            }
#pragma unroll
            for (int off = 8; off <= 32; off <<= 1) {
#pragma unroll
                for (int j = 0; j < 4; ++j) {
                    f32x2 tt;
                    tt.x = __shfl_xor(acc[j].x, off);
                    tt.y = __shfl_xor(acc[j].y, off);
                    acc[j] += tt;
                }
            }
            if (slot == 0) {
                float inv = __builtin_amdgcn_rcpf(fmaxf((float)(end - start), 1.0f));
                ushort_t rr[8];
                *(uint4*)rr = *(const uint4*)(h1r + (size_t)row * HID_C + part * 8);
                ushort_t o[8];
                o[0] = f2bfu(fmaxf(acc[0].x * inv + bfu2f(rr[0]) + bb0.x, 0.f));
                o[1] = f2bfu(fmaxf(acc[0].y * inv + bfu2f(rr[1]) + bb0.y, 0.f));
                o[2] = f2bfu(fmaxf(acc[1].x * inv + bfu2f(rr[2]) + bb0.z, 0.f));
                o[3] = f2bfu(fmaxf(acc[1].y * inv + bfu2f(rr[3]) + bb0.w, 0.f));
                o[4] = f2bfu(fmaxf(acc[2].x * inv + bfu2f(rr[4]) + bb1.x, 0.f));
                o[5] = f2bfu(fmaxf(acc[2].y * inv + bfu2f(rr[5]) + bb1.y, 0.f));
                o[6] = f2bfu(fmaxf(acc[3].x * inv + bfu2f(rr[6]) + bb1.z, 0.f));
                o[7] = f2bfu(fmaxf(acc[3].y * inv + bfu2f(rr[7]) + bb1.w, 0.f));
                *(uint4*)(hs + lrow * 72 + part * 8) = *(const uint4*)o;
            }
        } else if (slot == 0) {
            uint4 z = make_uint4(0u, 0u, 0u, 0u);
            *(uint4*)(hs + lrow * 72 + part * 8) = z;
        }
    }
    __syncthreads();

    // ---- phase B: gemm2 MFMA from LDS
    const int m = lane & 15, quad = lane >> 4;
    const int m0 = wv * 16;

    bf16x8 a[2];
#pragma unroll
    for (int kk = 0; kk < 2; ++kk)
        a[kk] = *(const bf16x8*)(hs + (m0 + m) * 72 + kk * 32 + quad * 8);

    f32x4 acc[5];
#pragma unroll
    for (int nt = 0; nt < 5; ++nt) acc[nt] = (f32x4){0.f, 0.f, 0.f, 0.f};

#pragma unroll
    for (int nt = 0; nt < 5; ++nt) {
#pragma unroll
        for (int kk = 0; kk < 2; ++kk) {
            bf16x8 b = *(const bf16x8*)(wsm + (nt * 16 + m) * 72 + kk * 32 + quad * 8);
            acc[nt] = __builtin_amdgcn_mfma_f32_16x16x32_bf16(a[kk], b, acc[nt], 0, 0, 0);
        }
    }

    const int grow_base = row_base + m0 + quad * 4;
#pragma unroll
    for (int r = 0; r < 4; ++r) {
        int grow = grow_base + r;
        if (grow < N_NODES) {
#pragma unroll
            for (int nt = 0; nt < 5; ++nt) {
                int col = nt * 16 + m;
                float v = acc[nt][r];
                if (col < OUT_C) h2l[(size_t)grow * 64 + col] = f2fp8(v);
                else             h2r[(size_t)grow * OUT_C + (col - OUT_C)] = f2bfu(v);
            }
        }
    }
}

// ================================================================ agg2: 8-slot uint2 gather of fp8 h2l (40B in 64B stride)
// csr byte-offsets; packed-f32 accumulation; static-xor reduce; native-exp log_softmax
__global__ __launch_bounds__(256) void k_agg2(const int* __restrict__ rowptr, const int* __restrict__ csr,
                                              const uchar_t* __restrict__ h2l, const ushort_t* __restrict__ h2r,
                                              const float* __restrict__ b2, float* __restrict__ out) {
    int row = (blockIdx.x * 256 + threadIdx.x) >> 6;
    int lane = threadIdx.x & 63;
    if (row >= N_NODES) return;
    int2 rp = *(const int2*)(rowptr + row);
    int start = rp.x, end = rp.y;
    const int slot = lane >> 3;
    const int part = lane & 7;
    f32x2 acc[4];
#pragma unroll
    for (int j = 0; j < 4; ++j) acc[j] = (f32x2){0.f, 0.f};

    int base = start;
    for (; base + 8 <= end; base += 8) {
        int s = csr[base + slot];                       // byte offset
        uint2 u = *(const uint2*)(h2l + s + part * 8);
        acc[0] += __builtin_amdgcn_cvt_pk_f32_fp8(u.x, false);
        acc[1] += __builtin_amdgcn_cvt_pk_f32_fp8(u.x, true);
        acc[2] += __builtin_amdgcn_cvt_pk_f32_fp8(u.y, false);
        acc[3] += __builtin_amdgcn_cvt_pk_f32_fp8(u.y, true);
    }
    if (base < end) {
        int e = base + slot;
        int s = csr[min(e, end - 1)];
        uint2 u = *(const uint2*)(h2l + s + part * 8);
        if (e >= end) { u.x = 0u; u.y = 0u; }
        acc[0] += __builtin_amdgcn_cvt_pk_f32_fp8(u.x, false);
        acc[1] += __builtin_amdgcn_cvt_pk_f32_fp8(u.x, true);
        acc[2] += __builtin_amdgcn_cvt_pk_f32_fp8(u.y, false);
        acc[3] += __builtin_amdgcn_cvt_pk_f32_fp8(u.y, true);
    }
#pragma unroll
    for (int off = 8; off <= 32; off <<= 1) {
#pragma unroll
        for (int j = 0; j < 4; ++j) {
            f32x2 tt;
            tt.x = __shfl_xor(acc[j].x, off);
            tt.y = __shfl_xor(acc[j].y, off);
            acc[j] += tt;
        }
    }

    // slot-0 lanes with part<5 hold channels part*8 .. part*8+7
    const bool fin = (slot == 0) && (part < 5);
    float inv = __builtin_amdgcn_rcpf(fmaxf((float)(end - start), 1.0f));
    f32x2 v2[4];
    if (fin) {
        size_t bi = (size_t)row * OUT_C + part * 8;
        ushort_t rr[8];
        *(uint2*)&rr[0] = *(const uint2*)(h2r + bi);
        *(uint2*)&rr[4] = *(const uint2*)(h2r + bi + 4);
        float4 bb0 = *(const float4*)(b2 + part * 8);
        float4 bb1 = *(const float4*)(b2 + part * 8 + 4);
        v2[0] = (f32x2){acc[0].x * inv + bfu2f(rr[0]) + bb0.x, acc[0].y * inv + bfu2f(rr[1]) + bb0.y};
        v2[1] = (f32x2){acc[1].x * inv + bfu2f(rr[2]) + bb0.z, acc[1].y * inv + bfu2f(rr[3]) + bb0.w};
        v2[2] = (f32x2){acc[2].x * inv + bfu2f(rr[4]) + bb1.x, acc[2].y * inv + bfu2f(rr[5]) + bb1.y};
        v2[3] = (f32x2){acc[3].x * inv + bfu2f(rr[6]) + bb1.z, acc[3].y * inv + bfu2f(rr[7]) + bb1.w};
    } else {
#pragma unroll
        for (int j = 0; j < 4; ++j) v2[j] = (f32x2){-1e30f, -1e30f};
    }
    // softmax stats within the 8-lane group (non-fin lanes compute garbage, never write)
    f32x2 m2;
    m2.x = fmaxf(fmaxf(v2[0].x, v2[1].x), fmaxf(v2[2].x, v2[3].x));
    m2.y = fmaxf(fmaxf(v2[0].y, v2[1].y), fmaxf(v2[2].y, v2[3].y));
    float pm = fmaxf(m2.x, m2.y);
#pragma unroll
    for (int off = 1; off <= 4; off <<= 1) pm = fmaxf(pm, __shfl_xor(pm, off));
    float es = 0.f;
#pragma unroll
    for (int j = 0; j < 4; ++j) {
        es += __expf(v2[j].x - pm);
        es += __expf(v2[j].y - pm);
    }
#pragma unroll
    for (int off = 1; off <= 4; off <<= 1) es += __shfl_xor(es, off);
    float ls = __logf(es);
    if (fin) {
        size_t bo = (size_t)row * OUT_C + part * 8;
        *(float4*)(out + bo) = make_float4(v2[0].x - pm - ls, v2[0].y - pm - ls,
                                           v2[1].x - pm - ls, v2[1].y - pm - ls);
        *(float4*)(out + bo + 4) = make_float4(v2[2].x - pm - ls, v2[2].y - pm - ls,
                                               v2[3].x - pm - ls, v2[3].y - pm - ls);
    }
}

// ----------------------------------------------------------------
extern "C" void kernel_launch(void* const* d_in, const int* in_sizes, int n_in,
                              void* d_out, int out_size, void* d_ws, size_t ws_size,
                              hipStream_t stream) {
    const float* x   = (const float*)d_in[0];
    const int*   ei  = (const int*)d_in[1];
    const float* Wl1 = (const float*)d_in[2];
    const float* b1  = (const float*)d_in[3];
    const float* Wr1 = (const float*)d_in[4];
    const float* Wl2 = (const float*)d_in[5];
    const float* b2  = (const float*)d_in[6];
    const float* Wr2 = (const float*)d_in[7];

    // ws layout (4B units): bucket int[196*9216] | bcur | rowptr[N+1] | csr[E] | [align16] |
    //   Wt1 bf16[128*128] | Wt2 bf16[80*64] | h1l fp8[N*64] | h1r bf16[N*64] |
    //   h2l fp8[N*64] | h2r bf16[N*40]
    size_t u = 0;
    int*      bucket = (int*)d_ws;             u += (size_t)NBUCK * BCAP;
    int*      bcur   = (int*)d_ws + u;         u += NBUCK + 4;
    int*      rowptr = (int*)d_ws + u;         u += N_NODES + 1;
    int*      csr    = (int*)d_ws + u;         u += E_EDGES;
    u = (u + 3) & ~(size_t)3;                  // 16B align
    ushort_t* Wt1    = (ushort_t*)((int*)d_ws + u); u += 128 * 128 / 2;
    ushort_t* Wt2    = (ushort_t*)((int*)d_ws + u); u += 80 * 64 / 2;
    uchar_t*  h1l    = (uchar_t*)((int*)d_ws + u);  u += (size_t)N_NODES * HID_C / 4;
    ushort_t* h1r    = (ushort_t*)((int*)d_ws + u); u += (size_t)N_NODES * HID_C / 2;
    uchar_t*  h2l    = (uchar_t*)((int*)d_ws + u);  u += (size_t)N_NODES * 64 / 4;
    ushort_t* h2r    = (ushort_t*)((int*)d_ws + u); u += (size_t)N_NODES * OUT_C / 2;
    if (ws_size < u * 4) return;

    hipMemsetAsync(bcur, 0, NBUCK * sizeof(int), stream);

    const int* src = ei;
    const int* dst = ei + E_EDGES;

    k_prep<<<B1_GRID + 64, 256, 0, stream>>>(src, dst, bcur, bucket, Wl1, Wr1, Wl2, Wr2, Wt1, Wt2);
    k_csr_gemm1<<<NBUCK + TILE_GRID, 256, 0, stream>>>(bucket, bcur, rowptr, csr, x, Wt1, h1l, h1r);
    k_agg1_gemm2<<<TILE_GRID, 256, 0, stream>>>(rowptr, csr, h1l, h1r, b1, Wt2, h2l, h2r);
    k_agg2<<<N_NODES / 4, 256, 0, stream>>>(rowptr, csr, h2l, h2r, b2, (float*)d_out);
}